// Round 4
// baseline (329.667 us; speedup 1.0000x reference)
//
#include <hip/hip_runtime.h>
#include <math.h>

#define B  2
#define L  4096
#define D  512
#define H  8
#define DH 64
#define BH (B * H)
#define K3 1536          // tripled-K for the bf16 split GEMM (Q,K)
#define XPW 1024         // Xp width: [hi | lo]

typedef short s16x8 __attribute__((ext_vector_type(8)));
typedef float f32x4 __attribute__((ext_vector_type(4)));

#define AS1 __attribute__((address_space(1)))
#define AS3 __attribute__((address_space(3)))

__device__ __forceinline__ void lds_load16(const void* g, void* l) {
    __builtin_amdgcn_global_load_lds((const AS1 unsigned int*)g,
                                     (AS3 unsigned int*)l, 16, 0, 0);
}

__device__ __forceinline__ unsigned short f2bf(float x) {
    union { float f; unsigned u; } v; v.f = x;
    unsigned u = v.u;
    return (unsigned short)((u + 0x7fff + ((u >> 16) & 1)) >> 16);
}
__device__ __forceinline__ float bf2f(unsigned short h) {
    union { float f; unsigned u; } v; v.u = ((unsigned)h) << 16;
    return v.f;
}

#define MEMFENCE asm volatile("" ::: "memory")
__device__ __forceinline__ void wg_bar() {
    MEMFENCE;
    __builtin_amdgcn_s_barrier();
    MEMFENCE;
}

// ---------------------------------------------------------------------------
// Fused prep: blocks [0,192) = split_w; [192, 12480) = split_x;
// [12480, 14528) = bias-init of Qb/Kb (split-K GEMM accumulates atomically
// into a bias-initialized C; stream order guarantees init precedes gemm).
// ---------------------------------------------------------------------------
__global__ __launch_bounds__(256)
void k_split(const float* __restrict__ q, const float* __restrict__ k,
             const float* __restrict__ v,
             const float* __restrict__ wq, const float* __restrict__ wk,
             const float* __restrict__ wv,
             unsigned short* __restrict__ Xp, unsigned short* __restrict__ WpT,
             float* __restrict__ Qb, float* __restrict__ Kb,
             const float* __restrict__ bq, const float* __restrict__ bk)
{
    const int tid = threadIdx.x;
    if (blockIdx.x < 192) {
        __shared__ float t[64][65];
        const int bx = blockIdx.x;
        const int e  = bx >> 6;
        const int k0 = (bx & 7) * 64;
        const int n0 = ((bx >> 3) & 7) * 64;
        const float* W = (e == 0) ? wq : (e == 1) ? wk : wv;

        for (int idx = tid; idx < 64 * 16; idx += 256) {
            const int i = idx >> 4, j4 = (idx & 15) << 2;
            *(float4*)&t[i][j4] = *(const float4*)(W + (size_t)(k0 + i) * 512 + n0 + j4);
        }
        __syncthreads();

        const int n_loc = tid >> 2;
        const int kq    = (tid & 3) << 4;
        unsigned short h[16], l[16];
        #pragma unroll
        for (int tt = 0; tt < 16; tt++) {
            const float x = t[kq + tt][n_loc];
            h[tt] = f2bf(x);
            l[tt] = f2bf(x - bf2f(h[tt]));
        }
        unsigned short* base = WpT + (size_t)e * 512 * K3 + (size_t)(n0 + n_loc) * K3 + k0 + kq;
        #pragma unroll
        for (int g4 = 0; g4 < 4; g4++) {
            ushort4 hv = make_ushort4(h[g4*4], h[g4*4+1], h[g4*4+2], h[g4*4+3]);
            ushort4 lv = make_ushort4(l[g4*4], l[g4*4+1], l[g4*4+2], l[g4*4+3]);
            *(ushort4*)(base + g4*4)        = hv;
            *(ushort4*)(base + 512 + g4*4)  = lv;
            *(ushort4*)(base + 1024 + g4*4) = hv;
        }
    } else if (blockIdx.x < 192 + 12288) {
        const size_t g = (size_t)(blockIdx.x - 192) * 256 + tid;
        const size_t per = (size_t)8192 * 128;
        const int e = (int)(g / per);
        const size_t rem = g - (size_t)e * per;
        const int m  = (int)(rem >> 7);
        const int kq = (int)(rem & 127) << 2;

        const float* X = (e == 0) ? q : (e == 1) ? k : v;
        const float4 x = *(const float4*)(X + (size_t)m * 512 + kq);

        unsigned short h0 = f2bf(x.x), h1 = f2bf(x.y), h2 = f2bf(x.z), h3 = f2bf(x.w);
        unsigned short* dst = Xp + (size_t)e * 8192 * XPW + (size_t)m * XPW + kq;
        *(ushort4*)(dst) = make_ushort4(h0, h1, h2, h3);
        if (e != 2) {
            unsigned short l0 = f2bf(x.x - bf2f(h0)), l1 = f2bf(x.y - bf2f(h1));
            unsigned short l2 = f2bf(x.z - bf2f(h2)), l3 = f2bf(x.w - bf2f(h3));
            *(ushort4*)(dst + 512) = make_ushort4(l0, l1, l2, l3);
        }
    } else {
        // bias-init: Qb/Kb[m][n] = bias[n]; 16 floats per thread.
        const int gi = blockIdx.x - (192 + 12288);          // 0..2047
        const size_t li = (size_t)gi * 4096 + (size_t)tid * 16;
        const size_t NEh = (size_t)8192 * 512;
        float* buf; const float* bias; size_t w;
        if (li < NEh) { buf = Qb; bias = bq; w = li; }
        else          { buf = Kb; bias = bk; w = li - NEh; }
        const int n = (int)(w & 511);
        const float4 b0 = *(const float4*)(bias + n);
        const float4 b1 = *(const float4*)(bias + n + 4);
        const float4 b2 = *(const float4*)(bias + n + 8);
        const float4 b3 = *(const float4*)(bias + n + 12);
        *(float4*)(buf + w)      = b0;
        *(float4*)(buf + w + 4)  = b1;
        *(float4*)(buf + w + 8)  = b2;
        *(float4*)(buf + w + 12) = b3;
    }
}

// ---------------------------------------------------------------------------
// Kernel 1: bf16-split MFMA GEMM, 256x256 tile, BK=64, 8 waves, 4-phase
// schedule per K-tile with counted vmcnt.  SPLIT-K: grid.z = 7 uniform
// chunks of 8 K-tiles (512 K-elems): z/3 = e (Q,K,V), z%3 = segment s.
// Segment map derived from the baseline loop (kA = k0<512 ? k0 : k0-512
// against B strip [hi|lo|hi]):
//   s=0: A hi (off 0)   . B hi (off 0)     = hi.hi
//   s=1: A hi (off 0)   . B lo (off 512)   = hi.lo
//   s=2: A lo (off 512) . B hi (off 1024)  = lo.hi
// Q/K chunks atomicAdd into bias-initialized C; V (single chunk, s=0)
// plain-stores with bias.
// LDS: A[2][256][64] + B[2][256][64] bf16 = 128 KiB, both-sides XOR swizzle.
// ---------------------------------------------------------------------------
#define MFMA16 __builtin_amdgcn_mfma_f32_16x16x32_bf16

__global__ __launch_bounds__(512, 2)
void gemm_mfma(const unsigned short* __restrict__ Xp,
               const unsigned short* __restrict__ WpT,
               const float* __restrict__ bq, const float* __restrict__ bk,
               const float* __restrict__ bv,
               float* __restrict__ Qo, float* __restrict__ Ko,
               float* __restrict__ Vo)
{
    __shared__ __align__(16) unsigned short lds[65536];   // 128 KiB

    const int z = blockIdx.z;
    const int e = z / 3;                  // 0,0,0,1,1,1,2
    const int s = z % 3;                  // 0,1,2,0,1,2,0
    const float* bias = (e == 0) ? bq : (e == 1) ? bk : bv;
    float* C          = (e == 0) ? Qo : (e == 1) ? Ko : Vo;
    const unsigned short* Ag = Xp  + (size_t)e * 8192 * XPW + (s == 2 ? 512 : 0);
    const unsigned short* Bg = WpT + (size_t)e * 512 * K3 + s * 512;
    const int NT = 8;                     // uniform: 8 K-tiles of 64

    const int tid  = threadIdx.x;
    const int lane = tid & 63;
    const int wid  = tid >> 6;            // 0..7
    const int wm   = wid & 1;             // 2 wave-rows  (128 rows each)
    const int wn   = wid >> 1;            // 4 wave-cols  (64 cols each)
    const int m0   = blockIdx.x * 256;
    const int n0g  = blockIdx.y * 256;

    // ---- staging addressing (pre-swizzled global source, linear LDS dest)
    const int srow = wid * 8 + (lane >> 3);               // 0..63
    const int scq8 = ((lane & 7) ^ (lane >> 3)) << 3;     // element offset
    const unsigned short* aSrc = Ag + (size_t)(m0 + srow) * XPW + scq8;
    const unsigned short* bSrc = Bg + (size_t)(n0g + srow) * K3 + scq8;
    unsigned short* ldsA = lds;
    unsigned short* ldsB = lds + 32768;
    unsigned short* dA = ldsA + wid * 512;   // + lane*16B by HW
    unsigned short* dB = ldsB + wid * 512;

    // ---- fragment read addressing
    const int r16 = lane & 15, quad = lane >> 4;
    const int x3 = r16 & 7;
    const int c0 = ((quad ^ x3) << 4);          // ks=0 chunk byte offset
    const int c1 = (((4 | quad) ^ x3) << 4);    // ks=1
    const char* fA = (const char*)ldsA + (wm * 128 + r16) * 128;
    const char* fB = (const char*)ldsB + (wn * 64 + r16) * 128;

    f32x4 acc[8][4];
    #pragma unroll
    for (int i = 0; i < 8; i++)
        #pragma unroll
        for (int j = 0; j < 4; j++)
            acc[i][j] = (f32x4){0.f, 0.f, 0.f, 0.f};

    // ---- prologue: stage tile 0 -> buf0 (8 gloads/thread)
    #pragma unroll
    for (int j = 0; j < 4; j++)
        lds_load16(aSrc + (size_t)(j * 64) * XPW, dA + j * 4096);
    #pragma unroll
    for (int j = 0; j < 4; j++)
        lds_load16(bSrc + (size_t)(j * 64) * K3, dB + j * 4096);

    s16x8 aF[8], b0[4], b1[4];

    for (int t = 0; t < NT; ++t) {
        const int pa = (t & 1) << 15;            // compute-buffer byte offset
        const int na = (~t & 1) * 16384;         // stage-buffer ushort offset
        // ================= phase 1: stage A(t+1); wait tile t; (mh0 x nh0)
        if (t + 1 < NT) {
            const int ka = (t + 1) * 64;
            #pragma unroll
            for (int j = 0; j < 4; j++)
                lds_load16(aSrc + (size_t)(j * 64) * XPW + ka, dA + na + j * 4096);
            asm volatile("s_waitcnt vmcnt(4)" ::: "memory");   // tile t (8) landed
        } else {
            asm volatile("s_waitcnt vmcnt(0)" ::: "memory");
        }
        wg_bar();
        #pragma unroll
        for (int mq = 0; mq < 4; mq++) {
            aF[mq * 2]     = *(const s16x8*)(fA + pa + mq * 2048 + c0);
            aF[mq * 2 + 1] = *(const s16x8*)(fA + pa + mq * 2048 + c1);
        }
        #pragma unroll
        for (int nq = 0; nq < 2; nq++) {
            b0[nq * 2]     = *(const s16x8*)(fB + pa + nq * 2048 + c0);
            b0[nq * 2 + 1] = *(const s16x8*)(fB + pa + nq * 2048 + c1);
        }
        wg_bar();
        asm volatile("s_waitcnt lgkmcnt(0)" ::: "memory");
        __builtin_amdgcn_s_setprio(1);
        #pragma unroll
        for (int mq = 0; mq < 4; mq++)
            #pragma unroll
            for (int nq = 0; nq < 2; nq++) {
                acc[mq][nq] = MFMA16(aF[mq*2],   b0[nq*2],   acc[mq][nq], 0, 0, 0);
                acc[mq][nq] = MFMA16(aF[mq*2+1], b0[nq*2+1], acc[mq][nq], 0, 0, 0);
            }
        __builtin_amdgcn_s_setprio(0);
        wg_bar();
        // ================= phase 2: stage B(t+1); (mh0 x nh1)
        if (t + 1 < NT) {
            const int kb = (t + 1) * 64;
            #pragma unroll
            for (int j = 0; j < 4; j++)
                lds_load16(bSrc + (size_t)(j * 64) * K3 + kb, dB + na + j * 4096);
        }
        #pragma unroll
        for (int nq = 0; nq < 2; nq++) {
            b1[nq * 2]     = *(const s16x8*)(fB + pa + (2 + nq) * 2048 + c0);
            b1[nq * 2 + 1] = *(const s16x8*)(fB + pa + (2 + nq) * 2048 + c1);
        }
        wg_bar();
        asm volatile("s_waitcnt lgkmcnt(0)" ::: "memory");
        __builtin_amdgcn_s_setprio(1);
        #pragma unroll
        for (int mq = 0; mq < 4; mq++)
            #pragma unroll
            for (int nq = 0; nq < 2; nq++) {
                acc[mq][2+nq] = MFMA16(aF[mq*2],   b1[nq*2],   acc[mq][2+nq], 0, 0, 0);
                acc[mq][2+nq] = MFMA16(aF[mq*2+1], b1[nq*2+1], acc[mq][2+nq], 0, 0, 0);
            }
        __builtin_amdgcn_s_setprio(0);
        wg_bar();
        // ================= phase 3: read A mh1; (mh1 x nh1)
        #pragma unroll
        for (int mq = 0; mq < 4; mq++) {
            aF[mq * 2]     = *(const s16x8*)(fA + pa + 8192 + mq * 2048 + c0);
            aF[mq * 2 + 1] = *(const s16x8*)(fA + pa + 8192 + mq * 2048 + c1);
        }
        wg_bar();
        asm volatile("s_waitcnt lgkmcnt(0)" ::: "memory");
        __builtin_amdgcn_s_setprio(1);
        #pragma unroll
        for (int mq = 0; mq < 4; mq++)
            #pragma unroll
            for (int nq = 0; nq < 2; nq++) {
                acc[4+mq][2+nq] = MFMA16(aF[mq*2],   b1[nq*2],   acc[4+mq][2+nq], 0, 0, 0);
                acc[4+mq][2+nq] = MFMA16(aF[mq*2+1], b1[nq*2+1], acc[4+mq][2+nq], 0, 0, 0);
            }
        __builtin_amdgcn_s_setprio(0);
        wg_bar();
        // ================= phase 4: (mh1 x nh0), no reads
        __builtin_amdgcn_s_setprio(1);
        #pragma unroll
        for (int mq = 0; mq < 4; mq++)
            #pragma unroll
            for (int nq = 0; nq < 2; nq++) {
                acc[4+mq][nq] = MFMA16(aF[mq*2],   b0[nq*2],   acc[4+mq][nq], 0, 0, 0);
                acc[4+mq][nq] = MFMA16(aF[mq*2+1], b0[nq*2+1], acc[4+mq][nq], 0, 0, 0);
            }
        __builtin_amdgcn_s_setprio(0);
        wg_bar();
    }

    // ---- epilogue
    if (e == 2) {
        #pragma unroll
        for (int nt = 0; nt < 4; nt++) {
            const int col = n0g + wn * 64 + nt * 16 + r16;
            const float bb = bias[col];
            #pragma unroll
            for (int mt = 0; mt < 8; mt++) {
                const int row0 = m0 + wm * 128 + mt * 16 + quad * 4;
                #pragma unroll
                for (int i = 0; i < 4; i++)
                    C[(size_t)(row0 + i) * 512 + col] = acc[mt][nt][i] + bb;
            }
        }
    } else {
        #pragma unroll
        for (int nt = 0; nt < 4; nt++) {
            const int col = n0g + wn * 64 + nt * 16 + r16;
            #pragma unroll
            for (int mt = 0; mt < 8; mt++) {
                const int row0 = m0 + wm * 128 + mt * 16 + quad * 4;
                #pragma unroll
                for (int i = 0; i < 4; i++)
                    atomicAdd(&C[(size_t)(row0 + i) * 512 + col], acc[mt][nt][i]);
            }
        }
    }
}

// ---------------------------------------------------------------------------
// Fused: blocks [0,256) = chunk_sums; [256, 256+16384) = sample_m.
// sample_m blocks are XCD-SWIZZLED: flat index i -> bh = i & 15, so all
// blocks of one (b,h) land on XCD bh%8 and that bh's 1 MB K strip stays in
// ONE per-XCD L2.
// sample_m is LATENCY-bound, not BW-bound (6.8% HBM, 0 MFMA): all 3 index
// loads + all 12 K-row float4 gathers are issued before any arithmetic
// (S <= 48 structural: S = 5*ceil(ln 4096) = 45), Q row read directly from
// global (L2 broadcast) instead of LDS+barrier.
// ---------------------------------------------------------------------------
#define CH 64
__global__ __launch_bounds__(256)
void k_sample_chunks(const float* __restrict__ Q, const float* __restrict__ K,
                     const int* __restrict__ idx, float* __restrict__ m_out, int S,
                     const float* __restrict__ V, float* __restrict__ partial)
{
    const int tid = threadIdx.x;
    if (blockIdx.x < 256) {
        const int bid = blockIdx.x;
        const int c  = (bid & 15) * 4 + (tid >> 6);
        const int h  = (bid >> 4) & (H - 1);
        const int b  = bid >> 7;
        const int d  = tid & 63;
        const float* base = V + (size_t)b * L * D + h * DH + d + (size_t)(c * CH) * D;

        float vals[CH];
        #pragma unroll
        for (int i = 0; i < CH; i++) vals[i] = base[(size_t)i * D];

        float s0 = 0.f, s1 = 0.f, s2 = 0.f, s3 = 0.f;
        #pragma unroll
        for (int i = 0; i < CH; i += 4) {
            s0 += vals[i]; s1 += vals[i+1]; s2 += vals[i+2]; s3 += vals[i+3];
        }
        partial[((size_t)((b * H + h) * 64 + c)) * DH + d] = (s0 + s1) + (s2 + s3);
    } else {
        const int lane = tid & 63;
        const int wib  = tid >> 6;
        const int i    = blockIdx.x - 256;          // 0..16383
        const int bh   = i & 15;                    // XCD swizzle: bh fastest
        const int lg   = i >> 4;                    // l-group 0..1023
        const int l = lg * 4 + wib;
        const int h = bh & (H - 1);
        const int b = bh >> 3;
        const int widx = (bh << 12) | l;            // m_out index (b,h,l flat)

        const int r4 = lane >> 2;
        const int c4 = lane & 3;

        // Q fragment straight from global (row is L2/L1-resident, 16-lane
        // broadcast per address) — no LDS, no barrier.
        float4 qf[4];
        {
            const float4* qv = (const float4*)(Q + ((size_t)b * L + l) * D + h * DH);
            #pragma unroll
            for (int ii = 0; ii < 4; ii++) qf[ii] = qv[c4 + 4 * ii];
        }

        const float* Kb = K + (size_t)b * L * D + h * DH;
        const int* is = idx + (size_t)l * S;

        // all index loads up front (3 per lane), then all 12 gathers in flight
        int  jj[3];
        bool ok[3];
        #pragma unroll
        for (int p = 0; p < 3; p++) {
            const int sp = p * 16 + r4;
            ok[p] = sp < S;
            jj[p] = ok[p] ? is[sp] : 0;
        }
        float4 kv[3][4];
        #pragma unroll
        for (int p = 0; p < 3; p++) {
            const float4* Krow = (const float4*)(Kb + (size_t)jj[p] * D);
            #pragma unroll
            for (int ii = 0; ii < 4; ii++) kv[p][ii] = Krow[c4 + 4 * ii];
        }

        float vmax = -INFINITY, vsum = 0.f;
        #pragma unroll
        for (int p = 0; p < 3; p++) {
            float dot = 0.f;
            #pragma unroll
            for (int ii = 0; ii < 4; ii++) {
                const float4 kvv = kv[p][ii];
                const float4 qq = qf[ii];
                dot += qq.x * kvv.x + qq.y * kvv.y + qq.z * kvv.z + qq.w * kvv.w;
            }
            dot += __shfl_xor(dot, 1, 64);
            dot += __shfl_xor(dot, 2, 64);   // full dot now in all 4 lanes of quad
            if (ok[p]) {
                vmax = fmaxf(vmax, dot);
                if (c4 == 0) vsum += dot;
            }
        }
        // vmax equal within each quad; vsum nonzero only at c4==0 -> reduce
        // across quads only (offsets 32..4).
        #pragma unroll
        for (int off = 32; off >= 4; off >>= 1) {
            vmax = fmaxf(vmax, __shfl_xor(vmax, off, 64));
            vsum += __shfl_xor(vsum, off, 64);
        }
        if (lane == 0) m_out[widx] = vmax - vsum * (1.0f / (float)L);
    }
}

// ---------------------------------------------------------------------------
// Kernel 3: exact top-NT via 4-level byte radix-select. One block per (b,h).
// Also zeroes sums[] and writes the selected-row flag array.
// ---------------------------------------------------------------------------
__global__ __launch_bounds__(256)
void topk_kernel(const float* __restrict__ m_in, int* __restrict__ m_top,
                 float* __restrict__ sums, int* __restrict__ flags, int NT)
{
    __shared__ unsigned hist[256];
    __shared__ unsigned sfx[257];
    __shared__ int sh_b, sh_rem;
    __shared__ int cnt_gt, cnt_eq;
    __shared__ int eqlist[128];

    const float* m = m_in + (size_t)blockIdx.x * L;
    const int tid = threadIdx.x;
    int* out = m_top + blockIdx.x * NT;
    int* fl  = flags + (size_t)blockIdx.x * L;

    if (tid < NT) sums[blockIdx.x * NT + tid] = 0.f;
    for (int i = tid; i < L; i += 256) fl[i] = 0;

    unsigned uv[16];
    #pragma unroll
    for (int k = 0; k < 16; k++) {
        const float f = m[tid + k * 256];
        const unsigned x = __float_as_uint(f);
        uv[k] = (x & 0x80000000u) ? ~x : (x | 0x80000000u);
    }

    unsigned prefix = 0;
    int rem = NT;

    for (int level = 0; level < 4; level++) {
        const int shift = 24 - level * 8;
        hist[tid] = 0;
        if (tid == 0) { cnt_gt = 0; cnt_eq = 0; }
        __syncthreads();
        #pragma unroll
        for (int k = 0; k < 16; k++) {
            const bool part = (level == 0) || ((uv[k] >> (shift + 8)) == prefix);
            if (part) atomicAdd(&hist[(uv[k] >> shift) & 255], 1u);
        }
        __syncthreads();
        if (tid < 64) {
            const unsigned s0 = hist[4*tid+0], s1 = hist[4*tid+1];
            const unsigned s2 = hist[4*tid+2], s3 = hist[4*tid+3];
            const unsigned loc = s0 + s1 + s2 + s3;
            unsigned suf = loc;
            #pragma unroll
            for (int off = 1; off < 64; off <<= 1) {
                const unsigned t = __shfl_down(suf, off, 64);
                if (tid + off < 64) suf += t;
            }
            const unsigned tail = suf - loc;
            sfx[4*tid+3] = tail + s3;
            sfx[4*tid+2] = tail + s3 + s2;
            sfx[4*tid+1] = tail + s3 + s2 + s1;
            sfx[4*tid+0] = suf;
            if (tid == 0) sfx[256] = 0;
        }
        __syncthreads();
        if (sfx[tid + 1] < (unsigned)rem && (unsigned)rem <= sfx[tid]) {
            sh_b   = tid;
            sh_rem = rem - (int)sfx[tid + 1];
        }
        __syncthreads();
        prefix = (prefix << 8) | (unsigned)sh_b;
        rem    = sh_rem;
        __syncthreads();
    }

    const unsigned T = prefix;
    const int n_gt = NT - rem;

    #pragma unroll
    for (int k = 0; k < 16; k++) {
        if (uv[k] > T) {
            const int pos = atomicAdd(&cnt_gt, 1);
            out[pos] = tid + k * 256;
        } else if (uv[k] == T) {
            const int pos = atomicAdd(&cnt_eq, 1);
            if (pos < 128) eqlist[pos] = tid + k * 256;
        }
    }
    __syncthreads();
    if (tid == 0) {
        int n = cnt_eq < 128 ? cnt_eq : 128;
        for (int r = 0; r < rem; r++) {
            int best = 0x7fffffff, bi = 0;
            for (int i = 0; i < n; i++)
                if (eqlist[i] < best) { best = eqlist[i]; bi = i; }
            out[n_gt + r] = best;
            eqlist[bi] = 0x7fffffff;
        }
    }
    __syncthreads();
    if (tid < NT) fl[out[tid]] = 1;
}

// ---------------------------------------------------------------------------
// Fused: blocks [0,256) = cumsum_write; [256, 256+384) = attn_scores.
// ---------------------------------------------------------------------------
__global__ __launch_bounds__(256)
void k_cumsum_scores(const float* __restrict__ V, const float* __restrict__ partial,
                     const int* __restrict__ flags, float* __restrict__ out,
                     const float* __restrict__ Q, const float* __restrict__ K,
                     const int* __restrict__ m_top, float* __restrict__ scores,
                     float* __restrict__ sums, int NT)
{
    const int tid = threadIdx.x;
    if (blockIdx.x < 256) {
        const int bid = blockIdx.x;
        const int c  = (bid & 15) * 4 + (tid >> 6);
        const int h  = (bid >> 4) & (H - 1);
        const int b  = bid >> 7;
        const int d  = tid & 63;
        const size_t off = (size_t)b * L * D + h * DH + d + (size_t)(c * CH) * D;
        const float* base  = V   + off;
        float*       obase = out + off;
        const float* pb = partial + (size_t)((b * H + h) * 64) * DH + d;
        const int*   fp = flags + (size_t)(b * H + h) * L + c * CH;

        float vals[CH];
        #pragma unroll
        for (int i = 0; i < CH; i++) vals[i] = base[(size_t)i * D];

        float acc = 0.f;
        for (int cc = 0; cc < c; cc++) acc += pb[cc * DH];

        #pragma unroll
        for (int i = 0; i < CH; i++) {
            acc += vals[i];
            obase[(size_t)i * D] = fp[i] ? 0.f : acc;
        }
    } else {
        __shared__ float qsh[15][DH];
        __shared__ int   psh[15];

        const int rem2 = blockIdx.x - 256;
        const int bh = rem2 / 24;
        const int r2 = rem2 % 24;
        const int ug = r2 >> 3;
        const int jc = r2 & 7;
        const int h  = bh & (H - 1);
        const int b  = bh >> 3;
        const int j0 = jc * 512;

        for (int i = tid; i < 15 * DH; i += 256) {
            const int u = i >> 6, d = i & 63;
            const int p = m_top[bh * NT + ug * 15 + u];
            if (d == 0) psh[u] = p;
            qsh[u][d] = Q[((size_t)b * L + p) * D + h * DH + d];
        }
        __syncthreads();

        const float* Kb = K + (size_t)b * L * D + h * DH;
        const int ja = j0 + tid;
        const int jb = ja + 256;
        float4 k0[16], k1[16];
        {
            const float4* ra = (const float4*)(Kb + (size_t)ja * D);
            const float4* rb = (const float4*)(Kb + (size_t)jb * D);
            #pragma unroll
            for (int i = 0; i < 16; i++) { k0[i] = ra[i]; k1[i] = rb[i]; }
        }

        for (int u = 0; u < 15; u++) {
            const int p = psh[u];
            const float4* qv = (const float4*)qsh[u];
            float d0 = 0.f, d1 = 0.f;
            #pragma unroll
            for (int i = 0; i < 16; i++) {
                const float4 q4 = qv[i];
                d0 += q4.x * k0[i].x + q4.y * k0[i].y + q4.z * k0[i].z + q4.w * k0[i].w;
                d1 += q4.x * k1[i].x + q4.y * k1[i].y + q4.z * k1[i].z + q4.w * k1[i].w;
            }
            const float e0 = (ja <= p) ? __expf(d0 * 0.125f) : 0.f;
            const float e1 = (jb <= p) ? __expf(d1 * 0.125f) : 0.f;
            float* srow = scores + (size_t)(bh * NT + ug * 15 + u) * L;
            srow[ja] = e0;
            srow[jb] = e1;
            float t = e0 + e1;
            #pragma unroll
            for (int off = 32; off; off >>= 1) t += __shfl_xor(t, off, 64);
            if ((tid & 63) == 0) atomicAdd(&sums[bh * NT + ug * 15 + u], t);
        }
    }
}

// ---------------------------------------------------------------------------
// Kernel 6c: weighted-V accumulate into flag-zeroed output rows via atomics.
// ---------------------------------------------------------------------------
__global__ __launch_bounds__(256)
void attn_wv(const float* __restrict__ scores, const float* __restrict__ V,
             const int* __restrict__ m_top, const float* __restrict__ sums,
             float* __restrict__ out, int NT)
{
    __shared__ float ssh[45][64];
    __shared__ float sinv[45];
    __shared__ int   psh[45];

    const int bh = blockIdx.y;
    const int h  = bh & (H - 1);
    const int b  = bh >> 3;
    const int j0 = blockIdx.x * 64;
    const int tid = threadIdx.x;
    const int d   = tid & 63;
    const int w   = tid >> 6;

    if (tid < NT) {
        psh[tid]  = m_top[bh * NT + tid];
        sinv[tid] = 1.0f / sums[bh * NT + tid];
    }

    const float* Vb = V + (size_t)b * L * D + h * DH + d;
    float vreg[64];
    #pragma unroll
    for (int i = 0; i < 64; i++) vreg[i] = Vb[(size_t)(j0 + i) * D];

    __syncthreads();
    for (int i = tid; i < NT * 64; i += 256) {
        const int u = i >> 6, j = i & 63;
        ssh[u][j] = scores[(size_t)(bh * NT + u) * L + j0 + j] * sinv[u];
    }
    __syncthreads();

    for (int u = w; u < NT; u += 4) {
        const int p = psh[u];
        if (p < j0) continue;
        const float* wt = ssh[u];
        float acc = 0.f;
        #pragma unroll
        for (int i = 0; i < 64; i++) acc += wt[i] * vreg[i];
        atomicAdd(out + ((size_t)b * L + p) * D + h * DH + d, acc);
    }
}

// ---------------------------------------------------------------------------
extern "C" void kernel_launch(void* const* d_in, const int* in_sizes, int n_in,
                              void* d_out, int out_size, void* d_ws, size_t ws_size,
                              hipStream_t stream)
{
    const float* queries = (const float*)d_in[0];
    const float* keys    = (const float*)d_in[1];
    const float* values  = (const float*)d_in[2];
    const float* Wq      = (const float*)d_in[3];
    const float* bq      = (const float*)d_in[4];
    const float* Wk      = (const float*)d_in[5];
    const float* bk      = (const float*)d_in[6];
    const float* Wv      = (const float*)d_in[7];
    const float* bv      = (const float*)d_in[8];
    const int*   idx     = (const int*)d_in[9];
    float* out = (float*)d_out;

    const int S  = in_sizes[9] / L;   // sample_k = 45
    const int NT = S;

    const size_t NE = (size_t)B * L * D;
    float* Qb      = (float*)d_ws;
    float* Kb      = Qb + NE;
    float* Vb      = Kb + NE;
    float* m_buf   = Vb + NE;                           // BH*L
    float* cs_part = m_buf + (size_t)BH * L;            // BH*64*DH
    int*   m_top   = (int*)(cs_part + (size_t)BH * 64 * DH);
    float* sums    = (float*)(m_top + 1024);            // BH*NT
    int*   flags   = (int*)(sums + 1024);               // BH*L
    float* scores  = (float*)(flags + (size_t)BH * L);  // BH*NT*L
    unsigned short* Xp  = (unsigned short*)(scores + (size_t)BH * NT * L);
    unsigned short* WpT = Xp + (size_t)3 * 8192 * XPW;  // 3*512*K3

    k_split<<<192 + 3 * 8192 * 128 / 256 + 2048, 256, 0, stream>>>(
        queries, keys, values, Wq, Wk, Wv, Xp, WpT, Qb, Kb, bq, bk);

    gemm_mfma<<<dim3(8192 / 256, 512 / 256, 7), 512, 0, stream>>>(
        Xp, WpT, bq, bk, bv, Qb, Kb, Vb);

    k_sample_chunks<<<256 + BH * L / 4, 256, 0, stream>>>(
        Qb, Kb, idx, m_buf, S, Vb, cs_part);

    topk_kernel<<<BH, 256, 0, stream>>>(m_buf, m_top, sums, flags, NT);

    k_cumsum_scores<<<256 + 384, 256, 0, stream>>>(
        Vb, cs_part, flags, out, Qb, Kb, m_top, scores, sums, NT);

    attn_wv<<<dim3(64, BH), 256, 0, stream>>>(scores, Vb, m_top, sums, out, NT);
}

// Round 5
// 266.711 us; speedup vs baseline: 1.2360x; 1.2360x over previous
//
#include <hip/hip_runtime.h>
#include <math.h>

#define B  2
#define L  4096
#define D  512
#define H  8
#define DH 64
#define BH (B * H)
#define K3 1536          // tripled-K for the bf16 split GEMM (Q,K)
#define XPW 1024         // Xp width: [hi | lo]

typedef short s16x8 __attribute__((ext_vector_type(8)));
typedef float f32x4 __attribute__((ext_vector_type(4)));

#define AS1 __attribute__((address_space(1)))
#define AS3 __attribute__((address_space(3)))

__device__ __forceinline__ void lds_load16(const void* g, void* l) {
    __builtin_amdgcn_global_load_lds((const AS1 unsigned int*)g,
                                     (AS3 unsigned int*)l, 16, 0, 0);
}

__device__ __forceinline__ unsigned short f2bf(float x) {
    union { float f; unsigned u; } v; v.f = x;
    unsigned u = v.u;
    return (unsigned short)((u + 0x7fff + ((u >> 16) & 1)) >> 16);
}
__device__ __forceinline__ float bf2f(unsigned short h) {
    union { float f; unsigned u; } v; v.u = ((unsigned)h) << 16;
    return v.f;
}

#define MEMFENCE asm volatile("" ::: "memory")
__device__ __forceinline__ void wg_bar() {
    MEMFENCE;
    __builtin_amdgcn_s_barrier();
    MEMFENCE;
}

// ---------------------------------------------------------------------------
// Fused prep: blocks [0,192) = split_w; [192, 192+12288) = split_x.
// (reverted to round-1 form: no bias-init, gemm plain-stores with bias)
// ---------------------------------------------------------------------------
__global__ __launch_bounds__(256)
void k_split(const float* __restrict__ q, const float* __restrict__ k,
             const float* __restrict__ v,
             const float* __restrict__ wq, const float* __restrict__ wk,
             const float* __restrict__ wv,
             unsigned short* __restrict__ Xp, unsigned short* __restrict__ WpT)
{
    const int tid = threadIdx.x;
    if (blockIdx.x < 192) {
        __shared__ float t[64][65];
        const int bx = blockIdx.x;
        const int e  = bx >> 6;
        const int k0 = (bx & 7) * 64;
        const int n0 = ((bx >> 3) & 7) * 64;
        const float* W = (e == 0) ? wq : (e == 1) ? wk : wv;

        for (int idx = tid; idx < 64 * 16; idx += 256) {
            const int i = idx >> 4, j4 = (idx & 15) << 2;
            *(float4*)&t[i][j4] = *(const float4*)(W + (size_t)(k0 + i) * 512 + n0 + j4);
        }
        __syncthreads();

        const int n_loc = tid >> 2;
        const int kq    = (tid & 3) << 4;
        unsigned short h[16], l[16];
        #pragma unroll
        for (int tt = 0; tt < 16; tt++) {
            const float x = t[kq + tt][n_loc];
            h[tt] = f2bf(x);
            l[tt] = f2bf(x - bf2f(h[tt]));
        }
        unsigned short* base = WpT + (size_t)e * 512 * K3 + (size_t)(n0 + n_loc) * K3 + k0 + kq;
        #pragma unroll
        for (int g4 = 0; g4 < 4; g4++) {
            ushort4 hv = make_ushort4(h[g4*4], h[g4*4+1], h[g4*4+2], h[g4*4+3]);
            ushort4 lv = make_ushort4(l[g4*4], l[g4*4+1], l[g4*4+2], l[g4*4+3]);
            *(ushort4*)(base + g4*4)        = hv;
            *(ushort4*)(base + 512 + g4*4)  = lv;
            *(ushort4*)(base + 1024 + g4*4) = hv;
        }
    } else {
        const size_t g = (size_t)(blockIdx.x - 192) * 256 + tid;
        const size_t per = (size_t)8192 * 128;
        const int e = (int)(g / per);
        const size_t rem = g - (size_t)e * per;
        const int m  = (int)(rem >> 7);
        const int kq = (int)(rem & 127) << 2;

        const float* X = (e == 0) ? q : (e == 1) ? k : v;
        const float4 x = *(const float4*)(X + (size_t)m * 512 + kq);

        unsigned short h0 = f2bf(x.x), h1 = f2bf(x.y), h2 = f2bf(x.z), h3 = f2bf(x.w);
        unsigned short* dst = Xp + (size_t)e * 8192 * XPW + (size_t)m * XPW + kq;
        *(ushort4*)(dst) = make_ushort4(h0, h1, h2, h3);
        if (e != 2) {
            unsigned short l0 = f2bf(x.x - bf2f(h0)), l1 = f2bf(x.y - bf2f(h1));
            unsigned short l2 = f2bf(x.z - bf2f(h2)), l3 = f2bf(x.w - bf2f(h3));
            *(ushort4*)(dst + 512) = make_ushort4(l0, l1, l2, l3);
        }
    }
}

// ---------------------------------------------------------------------------
// Kernel 1: bf16-split MFMA GEMM, 256x256 tile, BK=64, 8 waves.
// Round-1 mapping restored (z=3, NT=24/8, plain store + bias).
// Inner loop restructured to the 2-barrier deep-pipeline shape:
//   stage ALL 8 t+1 loads -> vmcnt(8) -> bar -> ds_read fragments as plain
//   loads (compiler emits counted lgkmcnt) interleaved with 64 MFMA in the
//   SAME per-acc accumulation order -> bar.
// (was: 4 phases x {bar, ds_read, bar, lgkmcnt(0), MFMA, bar} = 12 barriers
// + 4 full drains per K-tile -> measured 5140 cyc/K-tile vs ~1200 floor)
// LDS: A[2][256][64] + B[2][256][64] bf16 = 128 KiB, both-sides XOR swizzle.
// ---------------------------------------------------------------------------
#define MFMA16 __builtin_amdgcn_mfma_f32_16x16x32_bf16

__global__ __launch_bounds__(512, 2)
void gemm_mfma(const unsigned short* __restrict__ Xp,
               const unsigned short* __restrict__ WpT,
               const float* __restrict__ bq, const float* __restrict__ bk,
               const float* __restrict__ bv,
               float* __restrict__ Qo, float* __restrict__ Ko,
               float* __restrict__ Vo)
{
    __shared__ __align__(16) unsigned short lds[65536];   // 128 KiB

    const int e = blockIdx.z;
    const float* bias = (e == 0) ? bq : (e == 1) ? bk : bv;
    float* C          = (e == 0) ? Qo : (e == 1) ? Ko : Vo;
    const unsigned short* Ag = Xp  + (size_t)e * 8192 * XPW;
    const unsigned short* Bg = WpT + (size_t)e * 512 * K3;
    const int NT = (e == 2) ? 8 : 24;     // K-tiles of 64

    const int tid  = threadIdx.x;
    const int lane = tid & 63;
    const int wid  = tid >> 6;            // 0..7
    const int wm   = wid & 1;             // 2 wave-rows  (128 rows each)
    const int wn   = wid >> 1;            // 4 wave-cols  (64 cols each)
    const int m0   = blockIdx.x * 256;
    const int n0g  = blockIdx.y * 256;

    // ---- staging addressing (pre-swizzled global source, linear LDS dest)
    const int srow = wid * 8 + (lane >> 3);               // 0..63
    const int scq8 = ((lane & 7) ^ (lane >> 3)) << 3;     // element offset
    const unsigned short* aSrc = Ag + (size_t)(m0 + srow) * XPW + scq8;
    const unsigned short* bSrc = Bg + (size_t)(n0g + srow) * K3 + scq8;
    unsigned short* ldsA = lds;
    unsigned short* ldsB = lds + 32768;
    unsigned short* dA = ldsA + wid * 512;   // + lane*16B by HW
    unsigned short* dB = ldsB + wid * 512;

    // ---- fragment read addressing
    const int r16 = lane & 15, quad = lane >> 4;
    const int x3 = r16 & 7;
    const int c0 = ((quad ^ x3) << 4);          // ks=0 chunk byte offset
    const int c1 = (((4 | quad) ^ x3) << 4);    // ks=1
    const char* fA = (const char*)ldsA + (wm * 128 + r16) * 128;
    const char* fB = (const char*)ldsB + (wn * 64 + r16) * 128;

    f32x4 acc[8][4];
    #pragma unroll
    for (int i = 0; i < 8; i++)
        #pragma unroll
        for (int j = 0; j < 4; j++)
            acc[i][j] = (f32x4){0.f, 0.f, 0.f, 0.f};

    // ---- prologue: stage tile 0 -> buf0 (8 gloads/thread)
    #pragma unroll
    for (int j = 0; j < 4; j++)
        lds_load16(aSrc + (size_t)(j * 64) * XPW, dA + j * 4096);
    #pragma unroll
    for (int j = 0; j < 4; j++)
        lds_load16(bSrc + (size_t)(j * 64) * K3, dB + j * 4096);

    s16x8 aF[8], b0[4], b1[4];

    for (int t = 0; t < NT; ++t) {
        const int pa = (t & 1) << 15;            // compute-buffer byte offset
        const int na = (~t & 1) * 16384;         // stage-buffer ushort offset

        // ---- stage ALL of tile t+1 (8 loads), then wait tile t landed.
        if (t + 1 < NT) {
            const int k1 = (t + 1) * 64;
            const int ka = (k1 < 512) ? k1 : k1 - 512;
            #pragma unroll
            for (int j = 0; j < 4; j++)
                lds_load16(aSrc + (size_t)(j * 64) * XPW + ka, dA + na + j * 4096);
            #pragma unroll
            for (int j = 0; j < 4; j++)
                lds_load16(bSrc + (size_t)(j * 64) * K3 + k1, dB + na + j * 4096);
            asm volatile("s_waitcnt vmcnt(8)" ::: "memory");   // tile t's 8 done
        } else {
            asm volatile("s_waitcnt vmcnt(0)" ::: "memory");
        }
        wg_bar();   // tile t fully staged by all waves

        // ---- fragments: A mh0 + all of B (plain loads; compiler emits
        //      fine-grained lgkmcnt and orders MFMA by data dependence)
        #pragma unroll
        for (int mq = 0; mq < 4; mq++) {
            aF[mq * 2]     = *(const s16x8*)(fA + pa + mq * 2048 + c0);
            aF[mq * 2 + 1] = *(const s16x8*)(fA + pa + mq * 2048 + c1);
        }
        #pragma unroll
        for (int nq = 0; nq < 2; nq++) {
            b0[nq * 2]     = *(const s16x8*)(fB + pa + nq * 2048 + c0);
            b0[nq * 2 + 1] = *(const s16x8*)(fB + pa + nq * 2048 + c1);
            b1[nq * 2]     = *(const s16x8*)(fB + pa + (2 + nq) * 2048 + c0);
            b1[nq * 2 + 1] = *(const s16x8*)(fB + pa + (2 + nq) * 2048 + c1);
        }
        __builtin_amdgcn_s_setprio(1);
        #pragma unroll
        for (int mq = 0; mq < 4; mq++)
            #pragma unroll
            for (int nq = 0; nq < 2; nq++) {
                acc[mq][nq]   = MFMA16(aF[mq*2],   b0[nq*2],   acc[mq][nq],   0, 0, 0);
                acc[mq][nq]   = MFMA16(aF[mq*2+1], b0[nq*2+1], acc[mq][nq],   0, 0, 0);
                acc[mq][2+nq] = MFMA16(aF[mq*2],   b1[nq*2],   acc[mq][2+nq], 0, 0, 0);
                acc[mq][2+nq] = MFMA16(aF[mq*2+1], b1[nq*2+1], acc[mq][2+nq], 0, 0, 0);
            }
        __builtin_amdgcn_s_setprio(0);

        // ---- fragments: A mh1 (reuse regs), second half of MFMAs
        #pragma unroll
        for (int mq = 0; mq < 4; mq++) {
            aF[mq * 2]     = *(const s16x8*)(fA + pa + 8192 + mq * 2048 + c0);
            aF[mq * 2 + 1] = *(const s16x8*)(fA + pa + 8192 + mq * 2048 + c1);
        }
        __builtin_amdgcn_s_setprio(1);
        #pragma unroll
        for (int mq = 0; mq < 4; mq++)
            #pragma unroll
            for (int nq = 0; nq < 2; nq++) {
                acc[4+mq][nq]   = MFMA16(aF[mq*2],   b0[nq*2],   acc[4+mq][nq],   0, 0, 0);
                acc[4+mq][nq]   = MFMA16(aF[mq*2+1], b0[nq*2+1], acc[4+mq][nq],   0, 0, 0);
                acc[4+mq][2+nq] = MFMA16(aF[mq*2],   b1[nq*2],   acc[4+mq][2+nq], 0, 0, 0);
                acc[4+mq][2+nq] = MFMA16(aF[mq*2+1], b1[nq*2+1], acc[4+mq][2+nq], 0, 0, 0);
            }
        __builtin_amdgcn_s_setprio(0);
        wg_bar();   // all waves done reading pa before next iter stages into it
    }

    // ---- epilogue
    #pragma unroll
    for (int nt = 0; nt < 4; nt++) {
        const int col = n0g + wn * 64 + nt * 16 + r16;
        const float bb = bias[col];
        #pragma unroll
        for (int mt = 0; mt < 8; mt++) {
            const int row0 = m0 + wm * 128 + mt * 16 + quad * 4;
            #pragma unroll
            for (int i = 0; i < 4; i++)
                C[(size_t)(row0 + i) * 512 + col] = acc[mt][nt][i] + bb;
        }
    }
}

// ---------------------------------------------------------------------------
// Fused: blocks [0,256) = chunk_sums; [256, 256+16384) = sample_m.
// sample_m blocks are XCD-SWIZZLED: flat index i -> bh = i & 15, so all
// blocks of one (b,h) land on XCD bh%8 and that bh's 1 MB K strip stays in
// ONE per-XCD L2.
// sample_m is LATENCY-bound, not BW-bound (6.8% HBM, 0 MFMA): all 3 index
// loads + all 12 K-row float4 gathers are issued before any arithmetic
// (S <= 48 structural: S = 5*ceil(ln 4096) = 45), Q row read directly from
// global (L2 broadcast) instead of LDS+barrier.
// ---------------------------------------------------------------------------
#define CH 64
__global__ __launch_bounds__(256)
void k_sample_chunks(const float* __restrict__ Q, const float* __restrict__ K,
                     const int* __restrict__ idx, float* __restrict__ m_out, int S,
                     const float* __restrict__ V, float* __restrict__ partial)
{
    const int tid = threadIdx.x;
    if (blockIdx.x < 256) {
        const int bid = blockIdx.x;
        const int c  = (bid & 15) * 4 + (tid >> 6);
        const int h  = (bid >> 4) & (H - 1);
        const int b  = bid >> 7;
        const int d  = tid & 63;
        const float* base = V + (size_t)b * L * D + h * DH + d + (size_t)(c * CH) * D;

        float vals[CH];
        #pragma unroll
        for (int i = 0; i < CH; i++) vals[i] = base[(size_t)i * D];

        float s0 = 0.f, s1 = 0.f, s2 = 0.f, s3 = 0.f;
        #pragma unroll
        for (int i = 0; i < CH; i += 4) {
            s0 += vals[i]; s1 += vals[i+1]; s2 += vals[i+2]; s3 += vals[i+3];
        }
        partial[((size_t)((b * H + h) * 64 + c)) * DH + d] = (s0 + s1) + (s2 + s3);
    } else {
        const int lane = tid & 63;
        const int wib  = tid >> 6;
        const int i    = blockIdx.x - 256;          // 0..16383
        const int bh   = i & 15;                    // XCD swizzle: bh fastest
        const int lg   = i >> 4;                    // l-group 0..1023
        const int l = lg * 4 + wib;
        const int h = bh & (H - 1);
        const int b = bh >> 3;
        const int widx = (bh << 12) | l;            // m_out index (b,h,l flat)

        const int r4 = lane >> 2;
        const int c4 = lane & 3;

        // Q fragment straight from global (row is L2/L1-resident, 16-lane
        // broadcast per address) — no LDS, no barrier.
        float4 qf[4];
        {
            const float4* qv = (const float4*)(Q + ((size_t)b * L + l) * D + h * DH);
            #pragma unroll
            for (int ii = 0; ii < 4; ii++) qf[ii] = qv[c4 + 4 * ii];
        }

        const float* Kb = K + (size_t)b * L * D + h * DH;
        const int* is = idx + (size_t)l * S;

        // all index loads up front (3 per lane), then all 12 gathers in flight
        int  jj[3];
        bool ok[3];
        #pragma unroll
        for (int p = 0; p < 3; p++) {
            const int sp = p * 16 + r4;
            ok[p] = sp < S;
            jj[p] = ok[p] ? is[sp] : 0;
        }
        float4 kv[3][4];
        #pragma unroll
        for (int p = 0; p < 3; p++) {
            const float4* Krow = (const float4*)(Kb + (size_t)jj[p] * D);
            #pragma unroll
            for (int ii = 0; ii < 4; ii++) kv[p][ii] = Krow[c4 + 4 * ii];
        }

        float vmax = -INFINITY, vsum = 0.f;
        #pragma unroll
        for (int p = 0; p < 3; p++) {
            float dot = 0.f;
            #pragma unroll
            for (int ii = 0; ii < 4; ii++) {
                const float4 kvv = kv[p][ii];
                const float4 qq = qf[ii];
                dot += qq.x * kvv.x + qq.y * kvv.y + qq.z * kvv.z + qq.w * kvv.w;
            }
            dot += __shfl_xor(dot, 1, 64);
            dot += __shfl_xor(dot, 2, 64);   // full dot now in all 4 lanes of quad
            if (ok[p]) {
                vmax = fmaxf(vmax, dot);
                if (c4 == 0) vsum += dot;
            }
        }
        // vmax equal within each quad; vsum nonzero only at c4==0 -> reduce
        // across quads only (offsets 32..4).
        #pragma unroll
        for (int off = 32; off >= 4; off >>= 1) {
            vmax = fmaxf(vmax, __shfl_xor(vmax, off, 64));
            vsum += __shfl_xor(vsum, off, 64);
        }
        if (lane == 0) m_out[widx] = vmax - vsum * (1.0f / (float)L);
    }
}

// ---------------------------------------------------------------------------
// Kernel 3: exact top-NT via 4-level byte radix-select. One block per (b,h).
// Also zeroes sums[] and writes the selected-row flag array.
// ---------------------------------------------------------------------------
__global__ __launch_bounds__(256)
void topk_kernel(const float* __restrict__ m_in, int* __restrict__ m_top,
                 float* __restrict__ sums, int* __restrict__ flags, int NT)
{
    __shared__ unsigned hist[256];
    __shared__ unsigned sfx[257];
    __shared__ int sh_b, sh_rem;
    __shared__ int cnt_gt, cnt_eq;
    __shared__ int eqlist[128];

    const float* m = m_in + (size_t)blockIdx.x * L;
    const int tid = threadIdx.x;
    int* out = m_top + blockIdx.x * NT;
    int* fl  = flags + (size_t)blockIdx.x * L;

    if (tid < NT) sums[blockIdx.x * NT + tid] = 0.f;
    for (int i = tid; i < L; i += 256) fl[i] = 0;

    unsigned uv[16];
    #pragma unroll
    for (int k = 0; k < 16; k++) {
        const float f = m[tid + k * 256];
        const unsigned x = __float_as_uint(f);
        uv[k] = (x & 0x80000000u) ? ~x : (x | 0x80000000u);
    }

    unsigned prefix = 0;
    int rem = NT;

    for (int level = 0; level < 4; level++) {
        const int shift = 24 - level * 8;
        hist[tid] = 0;
        if (tid == 0) { cnt_gt = 0; cnt_eq = 0; }
        __syncthreads();
        #pragma unroll
        for (int k = 0; k < 16; k++) {
            const bool part = (level == 0) || ((uv[k] >> (shift + 8)) == prefix);
            if (part) atomicAdd(&hist[(uv[k] >> shift) & 255], 1u);
        }
        __syncthreads();
        if (tid < 64) {
            const unsigned s0 = hist[4*tid+0], s1 = hist[4*tid+1];
            const unsigned s2 = hist[4*tid+2], s3 = hist[4*tid+3];
            const unsigned loc = s0 + s1 + s2 + s3;
            unsigned suf = loc;
            #pragma unroll
            for (int off = 1; off < 64; off <<= 1) {
                const unsigned t = __shfl_down(suf, off, 64);
                if (tid + off < 64) suf += t;
            }
            const unsigned tail = suf - loc;
            sfx[4*tid+3] = tail + s3;
            sfx[4*tid+2] = tail + s3 + s2;
            sfx[4*tid+1] = tail + s3 + s2 + s1;
            sfx[4*tid+0] = suf;
            if (tid == 0) sfx[256] = 0;
        }
        __syncthreads();
        if (sfx[tid + 1] < (unsigned)rem && (unsigned)rem <= sfx[tid]) {
            sh_b   = tid;
            sh_rem = rem - (int)sfx[tid + 1];
        }
        __syncthreads();
        prefix = (prefix << 8) | (unsigned)sh_b;
        rem    = sh_rem;
        __syncthreads();
    }

    const unsigned T = prefix;
    const int n_gt = NT - rem;

    #pragma unroll
    for (int k = 0; k < 16; k++) {
        if (uv[k] > T) {
            const int pos = atomicAdd(&cnt_gt, 1);
            out[pos] = tid + k * 256;
        } else if (uv[k] == T) {
            const int pos = atomicAdd(&cnt_eq, 1);
            if (pos < 128) eqlist[pos] = tid + k * 256;
        }
    }
    __syncthreads();
    if (tid == 0) {
        int n = cnt_eq < 128 ? cnt_eq : 128;
        for (int r = 0; r < rem; r++) {
            int best = 0x7fffffff, bi = 0;
            for (int i = 0; i < n; i++)
                if (eqlist[i] < best) { best = eqlist[i]; bi = i; }
            out[n_gt + r] = best;
            eqlist[bi] = 0x7fffffff;
        }
    }
    __syncthreads();
    if (tid < NT) fl[out[tid]] = 1;
}

// ---------------------------------------------------------------------------
// Fused: blocks [0,256) = cumsum_write; [256, 256+384) = attn_scores.
// ---------------------------------------------------------------------------
__global__ __launch_bounds__(256)
void k_cumsum_scores(const float* __restrict__ V, const float* __restrict__ partial,
                     const int* __restrict__ flags, float* __restrict__ out,
                     const float* __restrict__ Q, const float* __restrict__ K,
                     const int* __restrict__ m_top, float* __restrict__ scores,
                     float* __restrict__ sums, int NT)
{
    const int tid = threadIdx.x;
    if (blockIdx.x < 256) {
        const int bid = blockIdx.x;
        const int c  = (bid & 15) * 4 + (tid >> 6);
        const int h  = (bid >> 4) & (H - 1);
        const int b  = bid >> 7;
        const int d  = tid & 63;
        const size_t off = (size_t)b * L * D + h * DH + d + (size_t)(c * CH) * D;
        const float* base  = V   + off;
        float*       obase = out + off;
        const float* pb = partial + (size_t)((b * H + h) * 64) * DH + d;
        const int*   fp = flags + (size_t)(b * H + h) * L + c * CH;

        float vals[CH];
        #pragma unroll
        for (int i = 0; i < CH; i++) vals[i] = base[(size_t)i * D];

        float acc = 0.f;
        for (int cc = 0; cc < c; cc++) acc += pb[cc * DH];

        #pragma unroll
        for (int i = 0; i < CH; i++) {
            acc += vals[i];
            obase[(size_t)i * D] = fp[i] ? 0.f : acc;
        }
    } else {
        __shared__ float qsh[15][DH];
        __shared__ int   psh[15];

        const int rem2 = blockIdx.x - 256;
        const int bh = rem2 / 24;
        const int r2 = rem2 % 24;
        const int ug = r2 >> 3;
        const int jc = r2 & 7;
        const int h  = bh & (H - 1);
        const int b  = bh >> 3;
        const int j0 = jc * 512;

        for (int i = tid; i < 15 * DH; i += 256) {
            const int u = i >> 6, d = i & 63;
            const int p = m_top[bh * NT + ug * 15 + u];
            if (d == 0) psh[u] = p;
            qsh[u][d] = Q[((size_t)b * L + p) * D + h * DH + d];
        }
        __syncthreads();

        const float* Kb = K + (size_t)b * L * D + h * DH;
        const int ja = j0 + tid;
        const int jb = ja + 256;
        float4 k0[16], k1[16];
        {
            const float4* ra = (const float4*)(Kb + (size_t)ja * D);
            const float4* rb = (const float4*)(Kb + (size_t)jb * D);
            #pragma unroll
            for (int i = 0; i < 16; i++) { k0[i] = ra[i]; k1[i] = rb[i]; }
        }

        for (int u = 0; u < 15; u++) {
            const int p = psh[u];
            const float4* qv = (const float4*)qsh[u];
            float d0 = 0.f, d1 = 0.f;
            #pragma unroll
            for (int i = 0; i < 16; i++) {
                const float4 q4 = qv[i];
                d0 += q4.x * k0[i].x + q4.y * k0[i].y + q4.z * k0[i].z + q4.w * k0[i].w;
                d1 += q4.x * k1[i].x + q4.y * k1[i].y + q4.z * k1[i].z + q4.w * k1[i].w;
            }
            const float e0 = (ja <= p) ? __expf(d0 * 0.125f) : 0.f;
            const float e1 = (jb <= p) ? __expf(d1 * 0.125f) : 0.f;
            float* srow = scores + (size_t)(bh * NT + ug * 15 + u) * L;
            srow[ja] = e0;
            srow[jb] = e1;
            float t = e0 + e1;
            #pragma unroll
            for (int off = 32; off; off >>= 1) t += __shfl_xor(t, off, 64);
            if ((tid & 63) == 0) atomicAdd(&sums[bh * NT + ug * 15 + u], t);
        }
    }
}

// ---------------------------------------------------------------------------
// Kernel 6c: weighted-V accumulate into flag-zeroed output rows via atomics.
// ---------------------------------------------------------------------------
__global__ __launch_bounds__(256)
void attn_wv(const float* __restrict__ scores, const float* __restrict__ V,
             const int* __restrict__ m_top, const float* __restrict__ sums,
             float* __restrict__ out, int NT)
{
    __shared__ float ssh[45][64];
    __shared__ float sinv[45];
    __shared__ int   psh[45];

    const int bh = blockIdx.y;
    const int h  = bh & (H - 1);
    const int b  = bh >> 3;
    const int j0 = blockIdx.x * 64;
    const int tid = threadIdx.x;
    const int d   = tid & 63;
    const int w   = tid >> 6;

    if (tid < NT) {
        psh[tid]  = m_top[bh * NT + tid];
        sinv[tid] = 1.0f / sums[bh * NT + tid];
    }

    const float* Vb = V + (size_t)b * L * D + h * DH + d;
    float vreg[64];
    #pragma unroll
    for (int i = 0; i < 64; i++) vreg[i] = Vb[(size_t)(j0 + i) * D];

    __syncthreads();
    for (int i = tid; i < NT * 64; i += 256) {
        const int u = i >> 6, j = i & 63;
        ssh[u][j] = scores[(size_t)(bh * NT + u) * L + j0 + j] * sinv[u];
    }
    __syncthreads();

    for (int u = w; u < NT; u += 4) {
        const int p = psh[u];
        if (p < j0) continue;
        const float* wt = ssh[u];
        float acc = 0.f;
        #pragma unroll
        for (int i = 0; i < 64; i++) acc += wt[i] * vreg[i];
        atomicAdd(out + ((size_t)b * L + p) * D + h * DH + d, acc);
    }
}

// ---------------------------------------------------------------------------
extern "C" void kernel_launch(void* const* d_in, const int* in_sizes, int n_in,
                              void* d_out, int out_size, void* d_ws, size_t ws_size,
                              hipStream_t stream)
{
    const float* queries = (const float*)d_in[0];
    const float* keys    = (const float*)d_in[1];
    const float* values  = (const float*)d_in[2];
    const float* Wq      = (const float*)d_in[3];
    const float* bq      = (const float*)d_in[4];
    const float* Wk      = (const float*)d_in[5];
    const float* bk      = (const float*)d_in[6];
    const float* Wv      = (const float*)d_in[7];
    const float* bv      = (const float*)d_in[8];
    const int*   idx     = (const int*)d_in[9];
    float* out = (float*)d_out;

    const int S  = in_sizes[9] / L;   // sample_k = 45
    const int NT = S;

    const size_t NE = (size_t)B * L * D;
    float* Qb      = (float*)d_ws;
    float* Kb      = Qb + NE;
    float* Vb      = Kb + NE;
    float* m_buf   = Vb + NE;                           // BH*L
    float* cs_part = m_buf + (size_t)BH * L;            // BH*64*DH
    int*   m_top   = (int*)(cs_part + (size_t)BH * 64 * DH);
    float* sums    = (float*)(m_top + 1024);            // BH*NT
    int*   flags   = (int*)(sums + 1024);               // BH*L
    float* scores  = (float*)(flags + (size_t)BH * L);  // BH*NT*L
    unsigned short* Xp  = (unsigned short*)(scores + (size_t)BH * NT * L);
    unsigned short* WpT = Xp + (size_t)3 * 8192 * XPW;  // 3*512*K3

    k_split<<<192 + 3 * 8192 * 128 / 256, 256, 0, stream>>>(
        queries, keys, values, Wq, Wk, Wv, Xp, WpT);

    gemm_mfma<<<dim3(8192 / 256, 512 / 256, 3), 512, 0, stream>>>(
        Xp, WpT, bq, bk, bv, Qb, Kb, Vb);

    k_sample_chunks<<<256 + BH * L / 4, 256, 0, stream>>>(
        Qb, Kb, idx, m_buf, S, Vb, cs_part);

    topk_kernel<<<BH, 256, 0, stream>>>(m_buf, m_top, sums, flags, NT);

    k_cumsum_scores<<<256 + 384, 256, 0, stream>>>(
        Vb, cs_part, flags, out, Qb, Kb, m_top, scores, sums, NT);

    attn_wv<<<dim3(64, BH), 256, 0, stream>>>(scores, Vb, m_top, sums, out, NT);
}

// Round 6
// 262.221 us; speedup vs baseline: 1.2572x; 1.0171x over previous
//
#include <hip/hip_runtime.h>
#include <math.h>

#define B  2
#define L  4096
#define D  512
#define H  8
#define DH 64
#define BH (B * H)
#define K3 1536          // tripled-K layout kept for WpT (third copy unused now)
#define XPW 1024         // Xp width: [hi | lo]

typedef short s16x8 __attribute__((ext_vector_type(8)));
typedef float f32x4 __attribute__((ext_vector_type(4)));

#define AS1 __attribute__((address_space(1)))
#define AS3 __attribute__((address_space(3)))

__device__ __forceinline__ void lds_load16(const void* g, void* l) {
    __builtin_amdgcn_global_load_lds((const AS1 unsigned int*)g,
                                     (AS3 unsigned int*)l, 16, 0, 0);
}

__device__ __forceinline__ unsigned short f2bf(float x) {
    union { float f; unsigned u; } v; v.f = x;
    unsigned u = v.u;
    return (unsigned short)((u + 0x7fff + ((u >> 16) & 1)) >> 16);
}
__device__ __forceinline__ float bf2f(unsigned short h) {
    union { float f; unsigned u; } v; v.u = ((unsigned)h) << 16;
    return v.f;
}

#define MEMFENCE asm volatile("" ::: "memory")
__device__ __forceinline__ void wg_bar() {
    MEMFENCE;
    __builtin_amdgcn_s_barrier();
    MEMFENCE;
}

// ---------------------------------------------------------------------------
// Fused prep: blocks [0,192) = split_w; [192, 192+12288) = split_x.
// (third B-hi copy no longer written: fused GEMM reads hi/lo pieces directly)
// ---------------------------------------------------------------------------
__global__ __launch_bounds__(256)
void k_split(const float* __restrict__ q, const float* __restrict__ k,
             const float* __restrict__ v,
             const float* __restrict__ wq, const float* __restrict__ wk,
             const float* __restrict__ wv,
             unsigned short* __restrict__ Xp, unsigned short* __restrict__ WpT)
{
    const int tid = threadIdx.x;
    if (blockIdx.x < 192) {
        __shared__ float t[64][65];
        const int bx = blockIdx.x;
        const int e  = bx >> 6;
        const int k0 = (bx & 7) * 64;
        const int n0 = ((bx >> 3) & 7) * 64;
        const float* W = (e == 0) ? wq : (e == 1) ? wk : wv;

        for (int idx = tid; idx < 64 * 16; idx += 256) {
            const int i = idx >> 4, j4 = (idx & 15) << 2;
            *(float4*)&t[i][j4] = *(const float4*)(W + (size_t)(k0 + i) * 512 + n0 + j4);
        }
        __syncthreads();

        const int n_loc = tid >> 2;
        const int kq    = (tid & 3) << 4;
        unsigned short h[16], l[16];
        #pragma unroll
        for (int tt = 0; tt < 16; tt++) {
            const float x = t[kq + tt][n_loc];
            h[tt] = f2bf(x);
            l[tt] = f2bf(x - bf2f(h[tt]));
        }
        unsigned short* base = WpT + (size_t)e * 512 * K3 + (size_t)(n0 + n_loc) * K3 + k0 + kq;
        #pragma unroll
        for (int g4 = 0; g4 < 4; g4++) {
            ushort4 hv = make_ushort4(h[g4*4], h[g4*4+1], h[g4*4+2], h[g4*4+3]);
            ushort4 lv = make_ushort4(l[g4*4], l[g4*4+1], l[g4*4+2], l[g4*4+3]);
            *(ushort4*)(base + g4*4)        = hv;
            *(ushort4*)(base + 512 + g4*4)  = lv;
        }
    } else {
        const size_t g = (size_t)(blockIdx.x - 192) * 256 + tid;
        const size_t per = (size_t)8192 * 128;
        const int e = (int)(g / per);
        const size_t rem = g - (size_t)e * per;
        const int m  = (int)(rem >> 7);
        const int kq = (int)(rem & 127) << 2;

        const float* X = (e == 0) ? q : (e == 1) ? k : v;
        const float4 x = *(const float4*)(X + (size_t)m * 512 + kq);

        unsigned short h0 = f2bf(x.x), h1 = f2bf(x.y), h2 = f2bf(x.z), h3 = f2bf(x.w);
        unsigned short* dst = Xp + (size_t)e * 8192 * XPW + (size_t)m * XPW + kq;
        *(ushort4*)(dst) = make_ushort4(h0, h1, h2, h3);
        if (e != 2) {
            unsigned short l0 = f2bf(x.x - bf2f(h0)), l1 = f2bf(x.y - bf2f(h1));
            unsigned short l2 = f2bf(x.z - bf2f(h2)), l3 = f2bf(x.w - bf2f(h3));
            *(ushort4*)(dst + 512) = make_ushort4(l0, l1, l2, l3);
        }
    }
}

// ---------------------------------------------------------------------------
// Kernel 1: FUSED bf16-split MFMA GEMM, 256x256 tile, 8 waves.
// Per BK-32 chunk: stage pieces {Ah, Al, Bh, Bl} (4 x 16 KB), then compute
// all three products hi.hi + hi.lo + lo.hi from register-resident fragments:
//   read Ah(8), Bh(4), Bl(4); MFMA Ah.Bh (32) + Ah.Bl (32);
//   reload Al over Ah;        MFMA Al.Bh (32).
// vs the old tripled-K loop this is 1.5x less LDS traffic (reads 4.6->3.1 MB,
// staging 1.5->1.0 MB per block) at identical MFMA count -- the old structure
// was LDS-BW-bound (schedule-insensitive 52 us across 3 different schedules).
// LDS: 2 buffers x {Ah,Al,Bh,Bl}[256][32] = 128 KiB.  Swizzle: 16B-chunk pos
// ^= ((row>>1)&3) on both stage-source and read -> 2 lanes/bank (free).
// V (e==2): hi-only, pieces {Ah, Bh}, 32 MFMA/chunk.
// fp32 per-acc sum order is a permutation of the old one (chunk-interleaved
// products) -- ~1e-4 relative, absmax dominated by bf16 rounding.
// ---------------------------------------------------------------------------
#define MFMA16 __builtin_amdgcn_mfma_f32_16x16x32_bf16

__global__ __launch_bounds__(512, 2)
void gemm_mfma(const unsigned short* __restrict__ Xp,
               const unsigned short* __restrict__ WpT,
               const float* __restrict__ bq, const float* __restrict__ bk,
               const float* __restrict__ bv,
               float* __restrict__ Qo, float* __restrict__ Ko,
               float* __restrict__ Vo)
{
    __shared__ __align__(16) unsigned short lds[65536];   // 128 KiB

    const int e = blockIdx.z;
    const float* bias = (e == 0) ? bq : (e == 1) ? bk : bv;
    float* C          = (e == 0) ? Qo : (e == 1) ? Ko : Vo;
    const unsigned short* Ag = Xp  + (size_t)e * 8192 * XPW;
    const unsigned short* Bg = WpT + (size_t)e * 512 * K3;

    const int tid  = threadIdx.x;
    const int lane = tid & 63;
    const int wid  = tid >> 6;            // 0..7
    const int wm   = wid & 1;             // 2 wave-rows  (128 rows each)
    const int wn   = wid >> 1;            // 4 wave-cols  (64 cols each)
    const int m0   = blockIdx.x * 256;
    const int n0g  = blockIdx.y * 256;

    // ---- staging addressing: per piece, 2 insts/wave: inst i covers rows
    // [wid*32 + i*16, +16).  lane: row = +(lane>>2), LDS chunk-pos = lane&3.
    // source chunk = pos ^ ((row>>1)&3)  (row bits beyond 4 don't affect &3).
    const int srow = lane >> 2;                       // 0..15
    const int spos = lane & 3;
    const int sswz = (spos ^ ((srow >> 1) & 3)) << 3; // element offset 0/8/16/24
    const int row0 = wid * 32 + srow;
    const int row1 = row0 + 16;

    const unsigned short* aH0 = Ag + (size_t)(m0 + row0) * XPW + sswz;
    const unsigned short* aH1 = Ag + (size_t)(m0 + row1) * XPW + sswz;
    const unsigned short* aL0 = aH0 + 512;
    const unsigned short* aL1 = aH1 + 512;
    const unsigned short* bH0 = Bg + (size_t)(n0g + row0) * K3 + sswz;
    const unsigned short* bH1 = Bg + (size_t)(n0g + row1) * K3 + sswz;
    const unsigned short* bL0 = bH0 + 512;
    const unsigned short* bL1 = bH1 + 512;

    // wave-uniform LDS dest offsets (ushorts); piece offsets (ushorts):
    // Ah +0, Al +8192, Bh +16384, Bl +24576; buffer stride 32768.
    const int wr0 = wid * 1024;
    const int wr1 = wr0 + 512;

    // ---- fragment read addressing (per-lane constant part)
    const int r16 = lane & 15, quad = lane >> 4;
    const int laneOff = r16 * 64 + ((quad ^ ((r16 >> 1) & 3)) << 4);  // bytes
    const char* ldsC = (const char*)lds;

    f32x4 acc[8][4];
    #pragma unroll
    for (int i = 0; i < 8; i++)
        #pragma unroll
        for (int j = 0; j < 4; j++)
            acc[i][j] = (f32x4){0.f, 0.f, 0.f, 0.f};

    const int NT = 16;                    // BK-32 chunks over K=512

    if (e != 2) {
        // ================= Q/K: fused 3-product loop =================
        #define STAGE_QK(kk, nu) do {                                   \
            const int ka_ = (kk) * 32;                                  \
            unsigned short* dd_ = lds + (nu);                           \
            lds_load16(aH0 + ka_, dd_ + wr0);                           \
            lds_load16(aH1 + ka_, dd_ + wr1);                           \
            lds_load16(aL0 + ka_, dd_ + 8192  + wr0);                   \
            lds_load16(aL1 + ka_, dd_ + 8192  + wr1);                   \
            lds_load16(bH0 + ka_, dd_ + 16384 + wr0);                   \
            lds_load16(bH1 + ka_, dd_ + 16384 + wr1);                   \
            lds_load16(bL0 + ka_, dd_ + 24576 + wr0);                   \
            lds_load16(bL1 + ka_, dd_ + 24576 + wr1);                   \
        } while (0)

        STAGE_QK(0, 0);
        s16x8 aF[8], bh[4], bl[4];

        for (int t = 0; t < NT; ++t) {
            const int pa = (t & 1) << 16;          // compute-buffer bytes
            const int nu = (~t & 1) << 15;         // stage-buffer ushorts
            if (t + 1 < NT) {
                STAGE_QK(t + 1, nu);
                asm volatile("s_waitcnt vmcnt(8)" ::: "memory");  // chunk t landed
            } else {
                asm volatile("s_waitcnt vmcnt(0)" ::: "memory");
            }
            wg_bar();

            const char* base = ldsC + pa;
            const char* fAh = base + (wm * 128) * 64 + laneOff;
            const char* fAl = base + 16384 + (wm * 128) * 64 + laneOff;
            const char* fBh = base + 32768 + (wn * 64) * 64 + laneOff;
            const char* fBl = base + 49152 + (wn * 64) * 64 + laneOff;

            #pragma unroll
            for (int mq = 0; mq < 8; mq++) aF[mq] = *(const s16x8*)(fAh + mq * 1024);
            #pragma unroll
            for (int nq = 0; nq < 4; nq++) {
                bh[nq] = *(const s16x8*)(fBh + nq * 1024);
                bl[nq] = *(const s16x8*)(fBl + nq * 1024);
            }
            __builtin_amdgcn_s_setprio(1);
            #pragma unroll
            for (int mq = 0; mq < 8; mq++)
                #pragma unroll
                for (int nq = 0; nq < 4; nq++)
                    acc[mq][nq] = MFMA16(aF[mq], bh[nq], acc[mq][nq], 0, 0, 0);
            #pragma unroll
            for (int mq = 0; mq < 8; mq++)
                #pragma unroll
                for (int nq = 0; nq < 4; nq++)
                    acc[mq][nq] = MFMA16(aF[mq], bl[nq], acc[mq][nq], 0, 0, 0);
            __builtin_amdgcn_s_setprio(0);

            #pragma unroll
            for (int mq = 0; mq < 8; mq++) aF[mq] = *(const s16x8*)(fAl + mq * 1024);
            __builtin_amdgcn_s_setprio(1);
            #pragma unroll
            for (int mq = 0; mq < 8; mq++)
                #pragma unroll
                for (int nq = 0; nq < 4; nq++)
                    acc[mq][nq] = MFMA16(aF[mq], bh[nq], acc[mq][nq], 0, 0, 0);
            __builtin_amdgcn_s_setprio(0);
            wg_bar();
        }
    } else {
        // ================= V: hi-only =================
        #define STAGE_V(kk, nu) do {                                    \
            const int ka_ = (kk) * 32;                                  \
            unsigned short* dd_ = lds + (nu);                           \
            lds_load16(aH0 + ka_, dd_ + wr0);                           \
            lds_load16(aH1 + ka_, dd_ + wr1);                           \
            lds_load16(bH0 + ka_, dd_ + 16384 + wr0);                   \
            lds_load16(bH1 + ka_, dd_ + 16384 + wr1);                   \
        } while (0)

        STAGE_V(0, 0);
        s16x8 aF[8], bh[4];

        for (int t = 0; t < NT; ++t) {
            const int pa = (t & 1) << 16;
            const int nu = (~t & 1) << 15;
            if (t + 1 < NT) {
                STAGE_V(t + 1, nu);
                asm volatile("s_waitcnt vmcnt(4)" ::: "memory");
            } else {
                asm volatile("s_waitcnt vmcnt(0)" ::: "memory");
            }
            wg_bar();

            const char* base = ldsC + pa;
            const char* fAh = base + (wm * 128) * 64 + laneOff;
            const char* fBh = base + 32768 + (wn * 64) * 64 + laneOff;
            #pragma unroll
            for (int mq = 0; mq < 8; mq++) aF[mq] = *(const s16x8*)(fAh + mq * 1024);
            #pragma unroll
            for (int nq = 0; nq < 4; nq++) bh[nq] = *(const s16x8*)(fBh + nq * 1024);
            __builtin_amdgcn_s_setprio(1);
            #pragma unroll
            for (int mq = 0; mq < 8; mq++)
                #pragma unroll
                for (int nq = 0; nq < 4; nq++)
                    acc[mq][nq] = MFMA16(aF[mq], bh[nq], acc[mq][nq], 0, 0, 0);
            __builtin_amdgcn_s_setprio(0);
            wg_bar();
        }
    }

    // ---- epilogue
    #pragma unroll
    for (int nt = 0; nt < 4; nt++) {
        const int col = n0g + wn * 64 + nt * 16 + r16;
        const float bb = bias[col];
        #pragma unroll
        for (int mt = 0; mt < 8; mt++) {
            const int row0e = m0 + wm * 128 + mt * 16 + quad * 4;
            #pragma unroll
            for (int i = 0; i < 4; i++)
                C[(size_t)(row0e + i) * 512 + col] = acc[mt][nt][i] + bb;
        }
    }
}

// ---------------------------------------------------------------------------
// Fused: blocks [0,256) = chunk_sums; [256, 256+16384) = sample_m.
// sample_m blocks are XCD-SWIZZLED: flat index i -> bh = i & 15, so all
// blocks of one (b,h) land on XCD bh%8 and that bh's 1 MB K strip stays in
// ONE per-XCD L2.
// sample_m is LATENCY-bound, not BW-bound (6.8% HBM, 0 MFMA): all 3 index
// loads + all 12 K-row float4 gathers are issued before any arithmetic
// (S <= 48 structural: S = 5*ceil(ln 4096) = 45), Q row read directly from
// global (L2 broadcast) instead of LDS+barrier.
// ---------------------------------------------------------------------------
#define CH 64
__global__ __launch_bounds__(256)
void k_sample_chunks(const float* __restrict__ Q, const float* __restrict__ K,
                     const int* __restrict__ idx, float* __restrict__ m_out, int S,
                     const float* __restrict__ V, float* __restrict__ partial)
{
    const int tid = threadIdx.x;
    if (blockIdx.x < 256) {
        const int bid = blockIdx.x;
        const int c  = (bid & 15) * 4 + (tid >> 6);
        const int h  = (bid >> 4) & (H - 1);
        const int b  = bid >> 7;
        const int d  = tid & 63;
        const float* base = V + (size_t)b * L * D + h * DH + d + (size_t)(c * CH) * D;

        float vals[CH];
        #pragma unroll
        for (int i = 0; i < CH; i++) vals[i] = base[(size_t)i * D];

        float s0 = 0.f, s1 = 0.f, s2 = 0.f, s3 = 0.f;
        #pragma unroll
        for (int i = 0; i < CH; i += 4) {
            s0 += vals[i]; s1 += vals[i+1]; s2 += vals[i+2]; s3 += vals[i+3];
        }
        partial[((size_t)((b * H + h) * 64 + c)) * DH + d] = (s0 + s1) + (s2 + s3);
    } else {
        const int lane = tid & 63;
        const int wib  = tid >> 6;
        const int i    = blockIdx.x - 256;          // 0..16383
        const int bh   = i & 15;                    // XCD swizzle: bh fastest
        const int lg   = i >> 4;                    // l-group 0..1023
        const int l = lg * 4 + wib;
        const int h = bh & (H - 1);
        const int b = bh >> 3;
        const int widx = (bh << 12) | l;            // m_out index (b,h,l flat)

        const int r4 = lane >> 2;
        const int c4 = lane & 3;

        // Q fragment straight from global (row is L2/L1-resident, 16-lane
        // broadcast per address) — no LDS, no barrier.
        float4 qf[4];
        {
            const float4* qv = (const float4*)(Q + ((size_t)b * L + l) * D + h * DH);
            #pragma unroll
            for (int ii = 0; ii < 4; ii++) qf[ii] = qv[c4 + 4 * ii];
        }

        const float* Kb = K + (size_t)b * L * D + h * DH;
        const int* is = idx + (size_t)l * S;

        // all index loads up front (3 per lane), then all 12 gathers in flight
        int  jj[3];
        bool ok[3];
        #pragma unroll
        for (int p = 0; p < 3; p++) {
            const int sp = p * 16 + r4;
            ok[p] = sp < S;
            jj[p] = ok[p] ? is[sp] : 0;
        }
        float4 kv[3][4];
        #pragma unroll
        for (int p = 0; p < 3; p++) {
            const float4* Krow = (const float4*)(Kb + (size_t)jj[p] * D);
            #pragma unroll
            for (int ii = 0; ii < 4; ii++) kv[p][ii] = Krow[c4 + 4 * ii];
        }

        float vmax = -INFINITY, vsum = 0.f;
        #pragma unroll
        for (int p = 0; p < 3; p++) {
            float dot = 0.f;
            #pragma unroll
            for (int ii = 0; ii < 4; ii++) {
                const float4 kvv = kv[p][ii];
                const float4 qq = qf[ii];
                dot += qq.x * kvv.x + qq.y * kvv.y + qq.z * kvv.z + qq.w * kvv.w;
            }
            dot += __shfl_xor(dot, 1, 64);
            dot += __shfl_xor(dot, 2, 64);   // full dot now in all 4 lanes of quad
            if (ok[p]) {
                vmax = fmaxf(vmax, dot);
                if (c4 == 0) vsum += dot;
            }
        }
        // vmax equal within each quad; vsum nonzero only at c4==0 -> reduce
        // across quads only (offsets 32..4).
        #pragma unroll
        for (int off = 32; off >= 4; off >>= 1) {
            vmax = fmaxf(vmax, __shfl_xor(vmax, off, 64));
            vsum += __shfl_xor(vsum, off, 64);
        }
        if (lane == 0) m_out[widx] = vmax - vsum * (1.0f / (float)L);
    }
}

// ---------------------------------------------------------------------------
// Kernel 3: exact top-NT via 4-level byte radix-select. One block per (b,h).
// Also zeroes sums[] and writes the selected-row flag array.
// ---------------------------------------------------------------------------
__global__ __launch_bounds__(256)
void topk_kernel(const float* __restrict__ m_in, int* __restrict__ m_top,
                 float* __restrict__ sums, int* __restrict__ flags, int NT)
{
    __shared__ unsigned hist[256];
    __shared__ unsigned sfx[257];
    __shared__ int sh_b, sh_rem;
    __shared__ int cnt_gt, cnt_eq;
    __shared__ int eqlist[128];

    const float* m = m_in + (size_t)blockIdx.x * L;
    const int tid = threadIdx.x;
    int* out = m_top + blockIdx.x * NT;
    int* fl  = flags + (size_t)blockIdx.x * L;

    if (tid < NT) sums[blockIdx.x * NT + tid] = 0.f;
    for (int i = tid; i < L; i += 256) fl[i] = 0;

    unsigned uv[16];
    #pragma unroll
    for (int k = 0; k < 16; k++) {
        const float f = m[tid + k * 256];
        const unsigned x = __float_as_uint(f);
        uv[k] = (x & 0x80000000u) ? ~x : (x | 0x80000000u);
    }

    unsigned prefix = 0;
    int rem = NT;

    for (int level = 0; level < 4; level++) {
        const int shift = 24 - level * 8;
        hist[tid] = 0;
        if (tid == 0) { cnt_gt = 0; cnt_eq = 0; }
        __syncthreads();
        #pragma unroll
        for (int k = 0; k < 16; k++) {
            const bool part = (level == 0) || ((uv[k] >> (shift + 8)) == prefix);
            if (part) atomicAdd(&hist[(uv[k] >> shift) & 255], 1u);
        }
        __syncthreads();
        if (tid < 64) {
            const unsigned s0 = hist[4*tid+0], s1 = hist[4*tid+1];
            const unsigned s2 = hist[4*tid+2], s3 = hist[4*tid+3];
            const unsigned loc = s0 + s1 + s2 + s3;
            unsigned suf = loc;
            #pragma unroll
            for (int off = 1; off < 64; off <<= 1) {
                const unsigned t = __shfl_down(suf, off, 64);
                if (tid + off < 64) suf += t;
            }
            const unsigned tail = suf - loc;
            sfx[4*tid+3] = tail + s3;
            sfx[4*tid+2] = tail + s3 + s2;
            sfx[4*tid+1] = tail + s3 + s2 + s1;
            sfx[4*tid+0] = suf;
            if (tid == 0) sfx[256] = 0;
        }
        __syncthreads();
        if (sfx[tid + 1] < (unsigned)rem && (unsigned)rem <= sfx[tid]) {
            sh_b   = tid;
            sh_rem = rem - (int)sfx[tid + 1];
        }
        __syncthreads();
        prefix = (prefix << 8) | (unsigned)sh_b;
        rem    = sh_rem;
        __syncthreads();
    }

    const unsigned T = prefix;
    const int n_gt = NT - rem;

    #pragma unroll
    for (int k = 0; k < 16; k++) {
        if (uv[k] > T) {
            const int pos = atomicAdd(&cnt_gt, 1);
            out[pos] = tid + k * 256;
        } else if (uv[k] == T) {
            const int pos = atomicAdd(&cnt_eq, 1);
            if (pos < 128) eqlist[pos] = tid + k * 256;
        }
    }
    __syncthreads();
    if (tid == 0) {
        int n = cnt_eq < 128 ? cnt_eq : 128;
        for (int r = 0; r < rem; r++) {
            int best = 0x7fffffff, bi = 0;
            for (int i = 0; i < n; i++)
                if (eqlist[i] < best) { best = eqlist[i]; bi = i; }
            out[n_gt + r] = best;
            eqlist[bi] = 0x7fffffff;
        }
    }
    __syncthreads();
    if (tid < NT) fl[out[tid]] = 1;
}

// ---------------------------------------------------------------------------
// Fused: blocks [0,256) = cumsum_write; [256, 256+384) = attn_scores.
// ---------------------------------------------------------------------------
__global__ __launch_bounds__(256)
void k_cumsum_scores(const float* __restrict__ V, const float* __restrict__ partial,
                     const int* __restrict__ flags, float* __restrict__ out,
                     const float* __restrict__ Q, const float* __restrict__ K,
                     const int* __restrict__ m_top, float* __restrict__ scores,
                     float* __restrict__ sums, int NT)
{
    const int tid = threadIdx.x;
    if (blockIdx.x < 256) {
        const int bid = blockIdx.x;
        const int c  = (bid & 15) * 4 + (tid >> 6);
        const int h  = (bid >> 4) & (H - 1);
        const int b  = bid >> 7;
        const int d  = tid & 63;
        const size_t off = (size_t)b * L * D + h * DH + d + (size_t)(c * CH) * D;
        const float* base  = V   + off;
        float*       obase = out + off;
        const float* pb = partial + (size_t)((b * H + h) * 64) * DH + d;
        const int*   fp = flags + (size_t)(b * H + h) * L + c * CH;

        float vals[CH];
        #pragma unroll
        for (int i = 0; i < CH; i++) vals[i] = base[(size_t)i * D];

        float acc = 0.f;
        for (int cc = 0; cc < c; cc++) acc += pb[cc * DH];

        #pragma unroll
        for (int i = 0; i < CH; i++) {
            acc += vals[i];
            obase[(size_t)i * D] = fp[i] ? 0.f : acc;
        }
    } else {
        __shared__ float qsh[15][DH];
        __shared__ int   psh[15];

        const int rem2 = blockIdx.x - 256;
        const int bh = rem2 / 24;
        const int r2 = rem2 % 24;
        const int ug = r2 >> 3;
        const int jc = r2 & 7;
        const int h  = bh & (H - 1);
        const int b  = bh >> 3;
        const int j0 = jc * 512;

        for (int i = tid; i < 15 * DH; i += 256) {
            const int u = i >> 6, d = i & 63;
            const int p = m_top[bh * NT + ug * 15 + u];
            if (d == 0) psh[u] = p;
            qsh[u][d] = Q[((size_t)b * L + p) * D + h * DH + d];
        }
        __syncthreads();

        const float* Kb = K + (size_t)b * L * D + h * DH;
        const int ja = j0 + tid;
        const int jb = ja + 256;
        float4 k0[16], k1[16];
        {
            const float4* ra = (const float4*)(Kb + (size_t)ja * D);
            const float4* rb = (const float4*)(Kb + (size_t)jb * D);
            #pragma unroll
            for (int i = 0; i < 16; i++) { k0[i] = ra[i]; k1[i] = rb[i]; }
        }

        for (int u = 0; u < 15; u++) {
            const int p = psh[u];
            const float4* qv = (const float4*)qsh[u];
            float d0 = 0.f, d1 = 0.f;
            #pragma unroll
            for (int i = 0; i < 16; i++) {
                const float4 q4 = qv[i];
                d0 += q4.x * k0[i].x + q4.y * k0[i].y + q4.z * k0[i].z + q4.w * k0[i].w;
                d1 += q4.x * k1[i].x + q4.y * k1[i].y + q4.z * k1[i].z + q4.w * k1[i].w;
            }
            const float e0 = (ja <= p) ? __expf(d0 * 0.125f) : 0.f;
            const float e1 = (jb <= p) ? __expf(d1 * 0.125f) : 0.f;
            float* srow = scores + (size_t)(bh * NT + ug * 15 + u) * L;
            srow[ja] = e0;
            srow[jb] = e1;
            float t = e0 + e1;
            #pragma unroll
            for (int off = 32; off; off >>= 1) t += __shfl_xor(t, off, 64);
            if ((tid & 63) == 0) atomicAdd(&sums[bh * NT + ug * 15 + u], t);
        }
    }
}

// ---------------------------------------------------------------------------
// Kernel 6c: weighted-V accumulate into flag-zeroed output rows via atomics.
// ---------------------------------------------------------------------------
__global__ __launch_bounds__(256)
void attn_wv(const float* __restrict__ scores, const float* __restrict__ V,
             const int* __restrict__ m_top, const float* __restrict__ sums,
             float* __restrict__ out, int NT)
{
    __shared__ float ssh[45][64];
    __shared__ float sinv[45];
    __shared__ int   psh[45];

    const int bh = blockIdx.y;
    const int h  = bh & (H - 1);
    const int b  = bh >> 3;
    const int j0 = blockIdx.x * 64;
    const int tid = threadIdx.x;
    const int d   = tid & 63;
    const int w   = tid >> 6;

    if (tid < NT) {
        psh[tid]  = m_top[bh * NT + tid];
        sinv[tid] = 1.0f / sums[bh * NT + tid];
    }

    const float* Vb = V + (size_t)b * L * D + h * DH + d;
    float vreg[64];
    #pragma unroll
    for (int i = 0; i < 64; i++) vreg[i] = Vb[(size_t)(j0 + i) * D];

    __syncthreads();
    for (int i = tid; i < NT * 64; i += 256) {
        const int u = i >> 6, j = i & 63;
        ssh[u][j] = scores[(size_t)(bh * NT + u) * L + j0 + j] * sinv[u];
    }
    __syncthreads();

    for (int u = w; u < NT; u += 4) {
        const int p = psh[u];
        if (p < j0) continue;
        const float* wt = ssh[u];
        float acc = 0.f;
        #pragma unroll
        for (int i = 0; i < 64; i++) acc += wt[i] * vreg[i];
        atomicAdd(out + ((size_t)b * L + p) * D + h * DH + d, acc);
    }
}

// ---------------------------------------------------------------------------
extern "C" void kernel_launch(void* const* d_in, const int* in_sizes, int n_in,
                              void* d_out, int out_size, void* d_ws, size_t ws_size,
                              hipStream_t stream)
{
    const float* queries = (const float*)d_in[0];
    const float* keys    = (const float*)d_in[1];
    const float* values  = (const float*)d_in[2];
    const float* Wq      = (const float*)d_in[3];
    const float* bq      = (const float*)d_in[4];
    const float* Wk      = (const float*)d_in[5];
    const float* bk      = (const float*)d_in[6];
    const float* Wv      = (const float*)d_in[7];
    const float* bv      = (const float*)d_in[8];
    const int*   idx     = (const int*)d_in[9];
    float* out = (float*)d_out;

    const int S  = in_sizes[9] / L;   // sample_k = 45
    const int NT = S;

    const size_t NE = (size_t)B * L * D;
    float* Qb      = (float*)d_ws;
    float* Kb      = Qb + NE;
    float* Vb      = Kb + NE;
    float* m_buf   = Vb + NE;                           // BH*L
    float* cs_part = m_buf + (size_t)BH * L;            // BH*64*DH
    int*   m_top   = (int*)(cs_part + (size_t)BH * 64 * DH);
    float* sums    = (float*)(m_top + 1024);            // BH*NT
    int*   flags   = (int*)(sums + 1024);               // BH*L
    float* scores  = (float*)(flags + (size_t)BH * L);  // BH*NT*L
    unsigned short* Xp  = (unsigned short*)(scores + (size_t)BH * NT * L);
    unsigned short* WpT = Xp + (size_t)3 * 8192 * XPW;  // 3*512*K3

    k_split<<<192 + 3 * 8192 * 128 / 256, 256, 0, stream>>>(
        queries, keys, values, Wq, Wk, Wv, Xp, WpT);

    gemm_mfma<<<dim3(8192 / 256, 512 / 256, 3), 512, 0, stream>>>(
        Xp, WpT, bq, bk, bv, Qb, Kb, Vb);

    k_sample_chunks<<<256 + BH * L / 4, 256, 0, stream>>>(
        Qb, Kb, idx, m_buf, S, Vb, cs_part);

    topk_kernel<<<BH, 256, 0, stream>>>(m_buf, m_top, sums, flags, NT);

    k_cumsum_scores<<<256 + 384, 256, 0, stream>>>(
        Vb, cs_part, flags, out, Qb, Kb, m_top, scores, sums, NT);

    attn_wv<<<dim3(64, BH), 256, 0, stream>>>(scores, Vb, m_top, sums, out, NT);
}

// Round 7
// 250.019 us; speedup vs baseline: 1.3186x; 1.0488x over previous
//
#include <hip/hip_runtime.h>
#include <math.h>

#define B  2
#define L  4096
#define D  512
#define H  8
#define DH 64
#define BH (B * H)
#define K3 1536          // tripled-K layout kept for WpT (third copy unused now)
#define XPW 1024         // Xp width: [hi | lo]

typedef short s16x8 __attribute__((ext_vector_type(8)));
typedef float f32x4 __attribute__((ext_vector_type(4)));

#define AS1 __attribute__((address_space(1)))
#define AS3 __attribute__((address_space(3)))

__device__ __forceinline__ void lds_load16(const void* g, void* l) {
    __builtin_amdgcn_global_load_lds((const AS1 unsigned int*)g,
                                     (AS3 unsigned int*)l, 16, 0, 0);
}

__device__ __forceinline__ unsigned short f2bf(float x) {
    union { float f; unsigned u; } v; v.f = x;
    unsigned u = v.u;
    return (unsigned short)((u + 0x7fff + ((u >> 16) & 1)) >> 16);
}
__device__ __forceinline__ float bf2f(unsigned short h) {
    union { float f; unsigned u; } v; v.u = ((unsigned)h) << 16;
    return v.f;
}

#define MEMFENCE asm volatile("" ::: "memory")
__device__ __forceinline__ void wg_bar() {
    MEMFENCE;
    __builtin_amdgcn_s_barrier();
    MEMFENCE;
}

// ---------------------------------------------------------------------------
// Fused prep: blocks [0,192) = split_w; [192, 192+12288) = split_x.
// ---------------------------------------------------------------------------
__global__ __launch_bounds__(256)
void k_split(const float* __restrict__ q, const float* __restrict__ k,
             const float* __restrict__ v,
             const float* __restrict__ wq, const float* __restrict__ wk,
             const float* __restrict__ wv,
             unsigned short* __restrict__ Xp, unsigned short* __restrict__ WpT)
{
    const int tid = threadIdx.x;
    if (blockIdx.x < 192) {
        __shared__ float t[64][65];
        const int bx = blockIdx.x;
        const int e  = bx >> 6;
        const int k0 = (bx & 7) * 64;
        const int n0 = ((bx >> 3) & 7) * 64;
        const float* W = (e == 0) ? wq : (e == 1) ? wk : wv;

        for (int idx = tid; idx < 64 * 16; idx += 256) {
            const int i = idx >> 4, j4 = (idx & 15) << 2;
            *(float4*)&t[i][j4] = *(const float4*)(W + (size_t)(k0 + i) * 512 + n0 + j4);
        }
        __syncthreads();

        const int n_loc = tid >> 2;
        const int kq    = (tid & 3) << 4;
        unsigned short h[16], l[16];
        #pragma unroll
        for (int tt = 0; tt < 16; tt++) {
            const float x = t[kq + tt][n_loc];
            h[tt] = f2bf(x);
            l[tt] = f2bf(x - bf2f(h[tt]));
        }
        unsigned short* base = WpT + (size_t)e * 512 * K3 + (size_t)(n0 + n_loc) * K3 + k0 + kq;
        #pragma unroll
        for (int g4 = 0; g4 < 4; g4++) {
            ushort4 hv = make_ushort4(h[g4*4], h[g4*4+1], h[g4*4+2], h[g4*4+3]);
            ushort4 lv = make_ushort4(l[g4*4], l[g4*4+1], l[g4*4+2], l[g4*4+3]);
            *(ushort4*)(base + g4*4)        = hv;
            *(ushort4*)(base + 512 + g4*4)  = lv;
        }
    } else {
        const size_t g = (size_t)(blockIdx.x - 192) * 256 + tid;
        const size_t per = (size_t)8192 * 128;
        const int e = (int)(g / per);
        const size_t rem = g - (size_t)e * per;
        const int m  = (int)(rem >> 7);
        const int kq = (int)(rem & 127) << 2;

        const float* X = (e == 0) ? q : (e == 1) ? k : v;
        const float4 x = *(const float4*)(X + (size_t)m * 512 + kq);

        unsigned short h0 = f2bf(x.x), h1 = f2bf(x.y), h2 = f2bf(x.z), h3 = f2bf(x.w);
        unsigned short* dst = Xp + (size_t)e * 8192 * XPW + (size_t)m * XPW + kq;
        *(ushort4*)(dst) = make_ushort4(h0, h1, h2, h3);
        if (e != 2) {
            unsigned short l0 = f2bf(x.x - bf2f(h0)), l1 = f2bf(x.y - bf2f(h1));
            unsigned short l2 = f2bf(x.z - bf2f(h2)), l3 = f2bf(x.w - bf2f(h3));
            *(ushort4*)(dst + 512) = make_ushort4(l0, l1, l2, l3);
        }
    }
}

// ---------------------------------------------------------------------------
// Kernel 1: FUSED bf16-split MFMA GEMM, 128x128 tile, 4 waves, 64 KiB LDS ->
// TWO blocks resident per CU (was 256x256 / 128 KiB / 1 block/CU: every
// vmcnt/barrier stall was fully exposed -- 4 schedule variants all ~50 us,
// MfmaUtil stuck 21-22%).  Independent co-resident blocks overlap each
// other's staging stalls with MFMA (m103-config evidence: 912 TF at 128^2).
// Per BK-32 chunk: stage {Ah, Al, Bh, Bl}[128][32] (4 x 8 KB), compute
// hi.hi + hi.lo + lo.hi with register-resident fragments (same accumulation
// order as the passing round-5 kernel -> numerics unchanged).
// Swizzle: 16B-chunk pos ^= ((row>>1)&3) on stage-source and read (2 l/bank).
// V (e==2): hi-only.
// ---------------------------------------------------------------------------
#define MFMA16 __builtin_amdgcn_mfma_f32_16x16x32_bf16

__global__ __launch_bounds__(256, 2)
void gemm_mfma(const unsigned short* __restrict__ Xp,
               const unsigned short* __restrict__ WpT,
               const float* __restrict__ bq, const float* __restrict__ bk,
               const float* __restrict__ bv,
               float* __restrict__ Qo, float* __restrict__ Ko,
               float* __restrict__ Vo)
{
    __shared__ __align__(16) unsigned short lds[32768];   // 64 KiB

    const int e = blockIdx.z;
    const float* bias = (e == 0) ? bq : (e == 1) ? bk : bv;
    float* C          = (e == 0) ? Qo : (e == 1) ? Ko : Vo;
    const unsigned short* Ag = Xp  + (size_t)e * 8192 * XPW;
    const unsigned short* Bg = WpT + (size_t)e * 512 * K3;

    const int tid  = threadIdx.x;
    const int lane = tid & 63;
    const int wid  = tid >> 6;            // 0..3
    const int wm   = wid & 1;             // 2 wave-rows  (64 rows each)
    const int wn   = wid >> 1;            // 2 wave-cols  (64 cols each)
    const int m0   = blockIdx.x * 128;
    const int n0g  = blockIdx.y * 128;

    // ---- staging addressing: per piece 8 KB = 8 wave-inst; wave wid covers
    // rows [wid*32, +32) with 2 insts (16 rows each).  lane: row += lane>>2,
    // LDS 16B-chunk pos = lane&3; source chunk = pos ^ ((row>>1)&3).
    const int srow = lane >> 2;                       // 0..15
    const int spos = lane & 3;
    const int sswz = (spos ^ ((srow >> 1) & 3)) << 3; // element offset
    const int row0 = wid * 32 + srow;                 // 0..127
    const int row1 = row0 + 16;

    const unsigned short* aH0 = Ag + (size_t)(m0 + row0) * XPW + sswz;
    const unsigned short* aH1 = Ag + (size_t)(m0 + row1) * XPW + sswz;
    const unsigned short* aL0 = aH0 + 512;
    const unsigned short* aL1 = aH1 + 512;
    const unsigned short* bH0 = Bg + (size_t)(n0g + row0) * K3 + sswz;
    const unsigned short* bH1 = Bg + (size_t)(n0g + row1) * K3 + sswz;
    const unsigned short* bL0 = bH0 + 512;
    const unsigned short* bL1 = bH1 + 512;

    // wave-uniform LDS dest offsets (ushorts).  Piece offsets (ushorts):
    // Ah +0, Al +4096, Bh +8192, Bl +12288; buffer stride 16384 (32 KB).
    const int wr0 = wid * 1024;
    const int wr1 = wr0 + 512;

    // ---- fragment read addressing (per-lane constant part)
    const int r16 = lane & 15, quad = lane >> 4;
    const int laneOff = r16 * 64 + ((quad ^ ((r16 >> 1) & 3)) << 4);  // bytes
    const char* ldsC = (const char*)lds;

    f32x4 acc[4][4];
    #pragma unroll
    for (int i = 0; i < 4; i++)
        #pragma unroll
        for (int j = 0; j < 4; j++)
            acc[i][j] = (f32x4){0.f, 0.f, 0.f, 0.f};

    const int NT = 16;                    // BK-32 chunks over K=512

    if (e != 2) {
        // ================= Q/K: fused 3-product loop =================
        #define STAGE_QK(kk, nu) do {                                   \
            const int ka_ = (kk) * 32;                                  \
            unsigned short* dd_ = lds + (nu);                           \
            lds_load16(aH0 + ka_, dd_ + wr0);                           \
            lds_load16(aH1 + ka_, dd_ + wr1);                           \
            lds_load16(aL0 + ka_, dd_ + 4096  + wr0);                   \
            lds_load16(aL1 + ka_, dd_ + 4096  + wr1);                   \
            lds_load16(bH0 + ka_, dd_ + 8192  + wr0);                   \
            lds_load16(bH1 + ka_, dd_ + 8192  + wr1);                   \
            lds_load16(bL0 + ka_, dd_ + 12288 + wr0);                   \
            lds_load16(bL1 + ka_, dd_ + 12288 + wr1);                   \
        } while (0)

        STAGE_QK(0, 0);
        s16x8 aF[4], bh[4], bl[4];

        for (int t = 0; t < NT; ++t) {
            const int pa = (t & 1) << 15;          // compute-buffer bytes
            const int nu = (~t & 1) << 14;         // stage-buffer ushorts
            if (t + 1 < NT) {
                STAGE_QK(t + 1, nu);
                asm volatile("s_waitcnt vmcnt(8)" ::: "memory");  // chunk t landed
            } else {
                asm volatile("s_waitcnt vmcnt(0)" ::: "memory");
            }
            wg_bar();

            const char* base = ldsC + pa;
            const char* fAh = base + (wm * 64) * 64 + laneOff;
            const char* fAl = base + 8192  + (wm * 64) * 64 + laneOff;
            const char* fBh = base + 16384 + (wn * 64) * 64 + laneOff;
            const char* fBl = base + 24576 + (wn * 64) * 64 + laneOff;

            #pragma unroll
            for (int mq = 0; mq < 4; mq++) aF[mq] = *(const s16x8*)(fAh + mq * 1024);
            #pragma unroll
            for (int nq = 0; nq < 4; nq++) {
                bh[nq] = *(const s16x8*)(fBh + nq * 1024);
                bl[nq] = *(const s16x8*)(fBl + nq * 1024);
            }
            __builtin_amdgcn_s_setprio(1);
            #pragma unroll
            for (int mq = 0; mq < 4; mq++)
                #pragma unroll
                for (int nq = 0; nq < 4; nq++)
                    acc[mq][nq] = MFMA16(aF[mq], bh[nq], acc[mq][nq], 0, 0, 0);
            #pragma unroll
            for (int mq = 0; mq < 4; mq++)
                #pragma unroll
                for (int nq = 0; nq < 4; nq++)
                    acc[mq][nq] = MFMA16(aF[mq], bl[nq], acc[mq][nq], 0, 0, 0);
            __builtin_amdgcn_s_setprio(0);

            #pragma unroll
            for (int mq = 0; mq < 4; mq++) aF[mq] = *(const s16x8*)(fAl + mq * 1024);
            __builtin_amdgcn_s_setprio(1);
            #pragma unroll
            for (int mq = 0; mq < 4; mq++)
                #pragma unroll
                for (int nq = 0; nq < 4; nq++)
                    acc[mq][nq] = MFMA16(aF[mq], bh[nq], acc[mq][nq], 0, 0, 0);
            __builtin_amdgcn_s_setprio(0);
            wg_bar();
        }
    } else {
        // ================= V: hi-only =================
        #define STAGE_V(kk, nu) do {                                    \
            const int ka_ = (kk) * 32;                                  \
            unsigned short* dd_ = lds + (nu);                           \
            lds_load16(aH0 + ka_, dd_ + wr0);                           \
            lds_load16(aH1 + ka_, dd_ + wr1);                           \
            lds_load16(bH0 + ka_, dd_ + 8192 + wr0);                    \
            lds_load16(bH1 + ka_, dd_ + 8192 + wr1);                    \
        } while (0)

        STAGE_V(0, 0);
        s16x8 aF[4], bh[4];

        for (int t = 0; t < NT; ++t) {
            const int pa = (t & 1) << 15;
            const int nu = (~t & 1) << 14;
            if (t + 1 < NT) {
                STAGE_V(t + 1, nu);
                asm volatile("s_waitcnt vmcnt(4)" ::: "memory");
            } else {
                asm volatile("s_waitcnt vmcnt(0)" ::: "memory");
            }
            wg_bar();

            const char* base = ldsC + pa;
            const char* fAh = base + (wm * 64) * 64 + laneOff;
            const char* fBh = base + 16384 + (wn * 64) * 64 + laneOff;
            #pragma unroll
            for (int mq = 0; mq < 4; mq++) aF[mq] = *(const s16x8*)(fAh + mq * 1024);
            #pragma unroll
            for (int nq = 0; nq < 4; nq++) bh[nq] = *(const s16x8*)(fBh + nq * 1024);
            __builtin_amdgcn_s_setprio(1);
            #pragma unroll
            for (int mq = 0; mq < 4; mq++)
                #pragma unroll
                for (int nq = 0; nq < 4; nq++)
                    acc[mq][nq] = MFMA16(aF[mq], bh[nq], acc[mq][nq], 0, 0, 0);
            __builtin_amdgcn_s_setprio(0);
            wg_bar();
        }
    }

    // ---- epilogue
    #pragma unroll
    for (int nt = 0; nt < 4; nt++) {
        const int col = n0g + wn * 64 + nt * 16 + r16;
        const float bb = bias[col];
        #pragma unroll
        for (int mt = 0; mt < 4; mt++) {
            const int row0e = m0 + wm * 64 + mt * 16 + quad * 4;
            #pragma unroll
            for (int i = 0; i < 4; i++)
                C[(size_t)(row0e + i) * 512 + col] = acc[mt][nt][i] + bb;
        }
    }
}

// ---------------------------------------------------------------------------
// Fused: blocks [0,256) = chunk_sums; [256, 256+16384) = sample_m.
// sample_m blocks are XCD-SWIZZLED: flat index i -> bh = i & 15, so all
// blocks of one (b,h) land on XCD bh%8 and that bh's 1 MB K strip stays in
// ONE per-XCD L2.
// sample_m: all 3 index loads + all 12 K-row float4 gathers are issued
// before any arithmetic; Q row read directly from global.  Likely at an
// L2-request-rate roofline (~13M 64B line requests; ~14 req/cyc/XCD-L2).
// ---------------------------------------------------------------------------
#define CH 64
__global__ __launch_bounds__(256)
void k_sample_chunks(const float* __restrict__ Q, const float* __restrict__ K,
                     const int* __restrict__ idx, float* __restrict__ m_out, int S,
                     const float* __restrict__ V, float* __restrict__ partial)
{
    const int tid = threadIdx.x;
    if (blockIdx.x < 256) {
        const int bid = blockIdx.x;
        const int c  = (bid & 15) * 4 + (tid >> 6);
        const int h  = (bid >> 4) & (H - 1);
        const int b  = bid >> 7;
        const int d  = tid & 63;
        const float* base = V + (size_t)b * L * D + h * DH + d + (size_t)(c * CH) * D;

        float vals[CH];
        #pragma unroll
        for (int i = 0; i < CH; i++) vals[i] = base[(size_t)i * D];

        float s0 = 0.f, s1 = 0.f, s2 = 0.f, s3 = 0.f;
        #pragma unroll
        for (int i = 0; i < CH; i += 4) {
            s0 += vals[i]; s1 += vals[i+1]; s2 += vals[i+2]; s3 += vals[i+3];
        }
        partial[((size_t)((b * H + h) * 64 + c)) * DH + d] = (s0 + s1) + (s2 + s3);
    } else {
        const int lane = tid & 63;
        const int wib  = tid >> 6;
        const int i    = blockIdx.x - 256;          // 0..16383
        const int bh   = i & 15;                    // XCD swizzle: bh fastest
        const int lg   = i >> 4;                    // l-group 0..1023
        const int l = lg * 4 + wib;
        const int h = bh & (H - 1);
        const int b = bh >> 3;
        const int widx = (bh << 12) | l;            // m_out index (b,h,l flat)

        const int r4 = lane >> 2;
        const int c4 = lane & 3;

        // Q fragment straight from global (row is L2/L1-resident, 16-lane
        // broadcast per address) — no LDS, no barrier.
        float4 qf[4];
        {
            const float4* qv = (const float4*)(Q + ((size_t)b * L + l) * D + h * DH);
            #pragma unroll
            for (int ii = 0; ii < 4; ii++) qf[ii] = qv[c4 + 4 * ii];
        }

        const float* Kb = K + (size_t)b * L * D + h * DH;
        const int* is = idx + (size_t)l * S;

        // all index loads up front (3 per lane), then all 12 gathers in flight
        int  jj[3];
        bool ok[3];
        #pragma unroll
        for (int p = 0; p < 3; p++) {
            const int sp = p * 16 + r4;
            ok[p] = sp < S;
            jj[p] = ok[p] ? is[sp] : 0;
        }
        float4 kv[3][4];
        #pragma unroll
        for (int p = 0; p < 3; p++) {
            const float4* Krow = (const float4*)(Kb + (size_t)jj[p] * D);
            #pragma unroll
            for (int ii = 0; ii < 4; ii++) kv[p][ii] = Krow[c4 + 4 * ii];
        }

        float vmax = -INFINITY, vsum = 0.f;
        #pragma unroll
        for (int p = 0; p < 3; p++) {
            float dot = 0.f;
            #pragma unroll
            for (int ii = 0; ii < 4; ii++) {
                const float4 kvv = kv[p][ii];
                const float4 qq = qf[ii];
                dot += qq.x * kvv.x + qq.y * kvv.y + qq.z * kvv.z + qq.w * kvv.w;
            }
            dot += __shfl_xor(dot, 1, 64);
            dot += __shfl_xor(dot, 2, 64);   // full dot now in all 4 lanes of quad
            if (ok[p]) {
                vmax = fmaxf(vmax, dot);
                if (c4 == 0) vsum += dot;
            }
        }
        // vmax equal within each quad; vsum nonzero only at c4==0 -> reduce
        // across quads only (offsets 32..4).
        #pragma unroll
        for (int off = 32; off >= 4; off >>= 1) {
            vmax = fmaxf(vmax, __shfl_xor(vmax, off, 64));
            vsum += __shfl_xor(vsum, off, 64);
        }
        if (lane == 0) m_out[widx] = vmax - vsum * (1.0f / (float)L);
    }
}

// ---------------------------------------------------------------------------
// Kernel 3: exact top-NT via 4-level byte radix-select. One block per (b,h).
// Also zeroes sums[] and writes the selected-row flag array.
// ---------------------------------------------------------------------------
__global__ __launch_bounds__(256)
void topk_kernel(const float* __restrict__ m_in, int* __restrict__ m_top,
                 float* __restrict__ sums, int* __restrict__ flags, int NT)
{
    __shared__ unsigned hist[256];
    __shared__ unsigned sfx[257];
    __shared__ int sh_b, sh_rem;
    __shared__ int cnt_gt, cnt_eq;
    __shared__ int eqlist[128];

    const float* m = m_in + (size_t)blockIdx.x * L;
    const int tid = threadIdx.x;
    int* out = m_top + blockIdx.x * NT;
    int* fl  = flags + (size_t)blockIdx.x * L;

    if (tid < NT) sums[blockIdx.x * NT + tid] = 0.f;
    for (int i = tid; i < L; i += 256) fl[i] = 0;

    unsigned uv[16];
    #pragma unroll
    for (int k = 0; k < 16; k++) {
        const float f = m[tid + k * 256];
        const unsigned x = __float_as_uint(f);
        uv[k] = (x & 0x80000000u) ? ~x : (x | 0x80000000u);
    }

    unsigned prefix = 0;
    int rem = NT;

    for (int level = 0; level < 4; level++) {
        const int shift = 24 - level * 8;
        hist[tid] = 0;
        if (tid == 0) { cnt_gt = 0; cnt_eq = 0; }
        __syncthreads();
        #pragma unroll
        for (int k = 0; k < 16; k++) {
            const bool part = (level == 0) || ((uv[k] >> (shift + 8)) == prefix);
            if (part) atomicAdd(&hist[(uv[k] >> shift) & 255], 1u);
        }
        __syncthreads();
        if (tid < 64) {
            const unsigned s0 = hist[4*tid+0], s1 = hist[4*tid+1];
            const unsigned s2 = hist[4*tid+2], s3 = hist[4*tid+3];
            const unsigned loc = s0 + s1 + s2 + s3;
            unsigned suf = loc;
            #pragma unroll
            for (int off = 1; off < 64; off <<= 1) {
                const unsigned t = __shfl_down(suf, off, 64);
                if (tid + off < 64) suf += t;
            }
            const unsigned tail = suf - loc;
            sfx[4*tid+3] = tail + s3;
            sfx[4*tid+2] = tail + s3 + s2;
            sfx[4*tid+1] = tail + s3 + s2 + s1;
            sfx[4*tid+0] = suf;
            if (tid == 0) sfx[256] = 0;
        }
        __syncthreads();
        if (sfx[tid + 1] < (unsigned)rem && (unsigned)rem <= sfx[tid]) {
            sh_b   = tid;
            sh_rem = rem - (int)sfx[tid + 1];
        }
        __syncthreads();
        prefix = (prefix << 8) | (unsigned)sh_b;
        rem    = sh_rem;
        __syncthreads();
    }

    const unsigned T = prefix;
    const int n_gt = NT - rem;

    #pragma unroll
    for (int k = 0; k < 16; k++) {
        if (uv[k] > T) {
            const int pos = atomicAdd(&cnt_gt, 1);
            out[pos] = tid + k * 256;
        } else if (uv[k] == T) {
            const int pos = atomicAdd(&cnt_eq, 1);
            if (pos < 128) eqlist[pos] = tid + k * 256;
        }
    }
    __syncthreads();
    if (tid == 0) {
        int n = cnt_eq < 128 ? cnt_eq : 128;
        for (int r = 0; r < rem; r++) {
            int best = 0x7fffffff, bi = 0;
            for (int i = 0; i < n; i++)
                if (eqlist[i] < best) { best = eqlist[i]; bi = i; }
            out[n_gt + r] = best;
            eqlist[bi] = 0x7fffffff;
        }
    }
    __syncthreads();
    if (tid < NT) fl[out[tid]] = 1;
}

// ---------------------------------------------------------------------------
// Fused: blocks [0,256) = cumsum_write; [256, 256+384) = attn_scores.
// ---------------------------------------------------------------------------
__global__ __launch_bounds__(256)
void k_cumsum_scores(const float* __restrict__ V, const float* __restrict__ partial,
                     const int* __restrict__ flags, float* __restrict__ out,
                     const float* __restrict__ Q, const float* __restrict__ K,
                     const int* __restrict__ m_top, float* __restrict__ scores,
                     float* __restrict__ sums, int NT)
{
    const int tid = threadIdx.x;
    if (blockIdx.x < 256) {
        const int bid = blockIdx.x;
        const int c  = (bid & 15) * 4 + (tid >> 6);
        const int h  = (bid >> 4) & (H - 1);
        const int b  = bid >> 7;
        const int d  = tid & 63;
        const size_t off = (size_t)b * L * D + h * DH + d + (size_t)(c * CH) * D;
        const float* base  = V   + off;
        float*       obase = out + off;
        const float* pb = partial + (size_t)((b * H + h) * 64) * DH + d;
        const int*   fp = flags + (size_t)(b * H + h) * L + c * CH;

        float vals[CH];
        #pragma unroll
        for (int i = 0; i < CH; i++) vals[i] = base[(size_t)i * D];

        float acc = 0.f;
        for (int cc = 0; cc < c; cc++) acc += pb[cc * DH];

        #pragma unroll
        for (int i = 0; i < CH; i++) {
            acc += vals[i];
            obase[(size_t)i * D] = fp[i] ? 0.f : acc;
        }
    } else {
        __shared__ float qsh[15][DH];
        __shared__ int   psh[15];

        const int rem2 = blockIdx.x - 256;
        const int bh = rem2 / 24;
        const int r2 = rem2 % 24;
        const int ug = r2 >> 3;
        const int jc = r2 & 7;
        const int h  = bh & (H - 1);
        const int b  = bh >> 3;
        const int j0 = jc * 512;

        for (int i = tid; i < 15 * DH; i += 256) {
            const int u = i >> 6, d = i & 63;
            const int p = m_top[bh * NT + ug * 15 + u];
            if (d == 0) psh[u] = p;
            qsh[u][d] = Q[((size_t)b * L + p) * D + h * DH + d];
        }
        __syncthreads();

        const float* Kb = K + (size_t)b * L * D + h * DH;
        const int ja = j0 + tid;
        const int jb = ja + 256;
        float4 k0[16], k1[16];
        {
            const float4* ra = (const float4*)(Kb + (size_t)ja * D);
            const float4* rb = (const float4*)(Kb + (size_t)jb * D);
            #pragma unroll
            for (int i = 0; i < 16; i++) { k0[i] = ra[i]; k1[i] = rb[i]; }
        }

        for (int u = 0; u < 15; u++) {
            const int p = psh[u];
            const float4* qv = (const float4*)qsh[u];
            float d0 = 0.f, d1 = 0.f;
            #pragma unroll
            for (int i = 0; i < 16; i++) {
                const float4 q4 = qv[i];
                d0 += q4.x * k0[i].x + q4.y * k0[i].y + q4.z * k0[i].z + q4.w * k0[i].w;
                d1 += q4.x * k1[i].x + q4.y * k1[i].y + q4.z * k1[i].z + q4.w * k1[i].w;
            }
            const float e0 = (ja <= p) ? __expf(d0 * 0.125f) : 0.f;
            const float e1 = (jb <= p) ? __expf(d1 * 0.125f) : 0.f;
            float* srow = scores + (size_t)(bh * NT + ug * 15 + u) * L;
            srow[ja] = e0;
            srow[jb] = e1;
            float t = e0 + e1;
            #pragma unroll
            for (int off = 32; off; off >>= 1) t += __shfl_xor(t, off, 64);
            if ((tid & 63) == 0) atomicAdd(&sums[bh * NT + ug * 15 + u], t);
        }
    }
}

// ---------------------------------------------------------------------------
// Kernel 6c: weighted-V accumulate into flag-zeroed output rows via atomics.
// ---------------------------------------------------------------------------
__global__ __launch_bounds__(256)
void attn_wv(const float* __restrict__ scores, const float* __restrict__ V,
             const int* __restrict__ m_top, const float* __restrict__ sums,
             float* __restrict__ out, int NT)
{
    __shared__ float ssh[45][64];
    __shared__ float sinv[45];
    __shared__ int   psh[45];

    const int bh = blockIdx.y;
    const int h  = bh & (H - 1);
    const int b  = bh >> 3;
    const int j0 = blockIdx.x * 64;
    const int tid = threadIdx.x;
    const int d   = tid & 63;
    const int w   = tid >> 6;

    if (tid < NT) {
        psh[tid]  = m_top[bh * NT + tid];
        sinv[tid] = 1.0f / sums[bh * NT + tid];
    }

    const float* Vb = V + (size_t)b * L * D + h * DH + d;
    float vreg[64];
    #pragma unroll
    for (int i = 0; i < 64; i++) vreg[i] = Vb[(size_t)(j0 + i) * D];

    __syncthreads();
    for (int i = tid; i < NT * 64; i += 256) {
        const int u = i >> 6, j = i & 63;
        ssh[u][j] = scores[(size_t)(bh * NT + u) * L + j0 + j] * sinv[u];
    }
    __syncthreads();

    for (int u = w; u < NT; u += 4) {
        const int p = psh[u];
        if (p < j0) continue;
        const float* wt = ssh[u];
        float acc = 0.f;
        #pragma unroll
        for (int i = 0; i < 64; i++) acc += wt[i] * vreg[i];
        atomicAdd(out + ((size_t)b * L + p) * D + h * DH + d, acc);
    }
}

// ---------------------------------------------------------------------------
extern "C" void kernel_launch(void* const* d_in, const int* in_sizes, int n_in,
                              void* d_out, int out_size, void* d_ws, size_t ws_size,
                              hipStream_t stream)
{
    const float* queries = (const float*)d_in[0];
    const float* keys    = (const float*)d_in[1];
    const float* values  = (const float*)d_in[2];
    const float* Wq      = (const float*)d_in[3];
    const float* bq      = (const float*)d_in[4];
    const float* Wk      = (const float*)d_in[5];
    const float* bk      = (const float*)d_in[6];
    const float* Wv      = (const float*)d_in[7];
    const float* bv      = (const float*)d_in[8];
    const int*   idx     = (const int*)d_in[9];
    float* out = (float*)d_out;

    const int S  = in_sizes[9] / L;   // sample_k = 45
    const int NT = S;

    const size_t NE = (size_t)B * L * D;
    float* Qb      = (float*)d_ws;
    float* Kb      = Qb + NE;
    float* Vb      = Kb + NE;
    float* m_buf   = Vb + NE;                           // BH*L
    float* cs_part = m_buf + (size_t)BH * L;            // BH*64*DH
    int*   m_top   = (int*)(cs_part + (size_t)BH * 64 * DH);
    float* sums    = (float*)(m_top + 1024);            // BH*NT
    int*   flags   = (int*)(sums + 1024);               // BH*L
    float* scores  = (float*)(flags + (size_t)BH * L);  // BH*NT*L
    unsigned short* Xp  = (unsigned short*)(scores + (size_t)BH * NT * L);
    unsigned short* WpT = Xp + (size_t)3 * 8192 * XPW;  // 3*512*K3

    k_split<<<192 + 3 * 8192 * 128 / 256, 256, 0, stream>>>(
        queries, keys, values, Wq, Wk, Wv, Xp, WpT);

    gemm_mfma<<<dim3(8192 / 128, 512 / 128, 3), 256, 0, stream>>>(
        Xp, WpT, bq, bk, bv, Qb, Kb, Vb);

    k_sample_chunks<<<256 + BH * L / 4, 256, 0, stream>>>(
        Qb, Kb, idx, m_buf, S, Vb, cs_part);

    topk_kernel<<<BH, 256, 0, stream>>>(m_buf, m_top, sums, flags, NT);

    k_cumsum_scores<<<256 + 384, 256, 0, stream>>>(
        Vb, cs_part, flags, out, Qb, Kb, m_top, scores, sums, NT);

    attn_wv<<<dim3(64, BH), 256, 0, stream>>>(scores, Vb, m_top, sums, out, NT);
}